// Round 1
// baseline (590.190 us; speedup 1.0000x reference)
//
#include <hip/hip_runtime.h>

typedef unsigned short u16;
typedef __bf16  bf16x8 __attribute__((ext_vector_type(8)));
typedef float   f32x4  __attribute__((ext_vector_type(4)));
typedef u16     u16x4  __attribute__((ext_vector_type(4)));

#define D_MODEL 1024
#define N_HEADS 16
#define HEAD_DIM 64
#define BATCH 4
#define SEQ 2048
#define MROWS (BATCH*SEQ)

__device__ __forceinline__ u16 f2bf(float f){
  unsigned u = __builtin_bit_cast(unsigned, f);
  u += 0x7fffu + ((u >> 16) & 1u);
  return (u16)(u >> 16);
}
__device__ __forceinline__ float bf2f(u16 h){
  unsigned u = ((unsigned)h) << 16;
  return __builtin_bit_cast(float, u);
}
__device__ __forceinline__ void gload_lds16(const u16* g, u16* l){
  __builtin_amdgcn_global_load_lds((const __attribute__((address_space(1))) void*)g,
                                   (__attribute__((address_space(3))) void*)l, 16, 0, 0);
}

// ---------- x fp32 -> bf16 ----------
__global__ void k_cvt_x(const float* __restrict__ x, u16* __restrict__ xb, int n4){
  int i = blockIdx.x * 256 + threadIdx.x;
  if (i >= n4) return;
  float4 v = reinterpret_cast<const float4*>(x)[i];
  u16x4 o;
  o.x = f2bf(v.x); o.y = f2bf(v.y); o.z = f2bf(v.z); o.w = f2bf(v.w);
  *reinterpret_cast<u16x4*>(xb + (size_t)i * 4) = o;
}

// ---------- W fp32 [k][n] -> bf16 Wt [n][k] ----------
__global__ void k_transpose_w(const float* __restrict__ Wq, const float* __restrict__ Wk,
                              const float* __restrict__ Wv, const float* __restrict__ Wo,
                              u16* __restrict__ wt){
  __shared__ float t[32][33];
  int z = blockIdx.z;
  const float* W = (z==0)?Wq:(z==1)?Wk:(z==2)?Wv:Wo;
  u16* O = wt + (size_t)z * (D_MODEL*(size_t)D_MODEL);
  int n0 = blockIdx.x*32, k0 = blockIdx.y*32;
  int tx = threadIdx.x, ty = threadIdx.y;
  #pragma unroll
  for (int i = ty; i < 32; i += 8) t[i][tx] = W[(size_t)(k0+i)*D_MODEL + n0 + tx];
  __syncthreads();
  #pragma unroll
  for (int i = ty; i < 32; i += 8) O[(size_t)(n0+i)*D_MODEL + k0 + tx] = f2bf(t[tx][i]);
}

// ---------- RoPE cos/sin table: tab[s*32+f] = (cos, sin) of pos[s]*theta^(-f/32) ----------
__global__ void k_rope_tab(const int* __restrict__ pos, float2* __restrict__ tab){
  int i = blockIdx.x * 256 + threadIdx.x;          // SEQ*32 threads
  int s = i >> 5, f = i & 31;
  float inv = exp2f(-(float)f * (13.287712379549449f / 32.0f)); // theta^(-f/32)
  float a = (float)pos[s] * inv;
  float sn, cs;
  sincosf(a, &sn, &cs);
  tab[i] = make_float2(cs, sn);
}

// ---------- GEMM: C[8192][1024] = A(bf16)[8192][1024] @ Bt(bf16)[1024][1024]^T ----------
// MODE 0: bf16 out, row-major. MODE 1: f32 out, row-major. MODE 2: bf16 out, Vt[b][h][d][s].
template<int MODE>
__global__ __launch_bounds__(256) void k_gemm(const u16* __restrict__ A, const u16* __restrict__ Bt,
                                              void* __restrict__ Cv){
  __shared__ u16 sA[128*32];
  __shared__ u16 sB[128*32];
  const int K = 1024, N = 1024;
  int tid = threadIdx.x, lane = tid & 63, w = tid >> 6;
  int lr = lane & 15, lg = lane >> 4;
  int m0 = blockIdx.x * 128, n0 = blockIdx.y * 128;
  int wr = w >> 1, wc = w & 1;
  int srow = lane >> 2;                       // staging row within 16-row stripe
  int schunk = (lane & 3) ^ (srow & 3);       // XOR-swizzled global chunk (rule 21)
  const u16* ga0 = A  + (size_t)(m0 + w*32 + srow)*K + schunk*8;
  const u16* gb0 = Bt + (size_t)(n0 + w*32 + srow)*K + schunk*8;
  u16* la = sA + (size_t)w*32*32;             // wave-uniform LDS base (lane*16B linear)
  u16* lb = sB + (size_t)w*32*32;
  f32x4 acc[4][4] = {};
  for (int k0 = 0; k0 < K; k0 += 32){
    gload_lds16(ga0 + k0,        la);
    gload_lds16(ga0 + 16*K + k0, la + 16*32);
    gload_lds16(gb0 + k0,        lb);
    gload_lds16(gb0 + 16*K + k0, lb + 16*32);
    __syncthreads();
    bf16x8 af[4], bfr[4];
    #pragma unroll
    for (int mi = 0; mi < 4; mi++){
      int row = wr*64 + mi*16 + lr;
      af[mi] = *(const bf16x8*)&sA[row*32 + ((lg ^ (row & 3)) * 8)];
    }
    #pragma unroll
    for (int ni = 0; ni < 4; ni++){
      int row = wc*64 + ni*16 + lr;
      bfr[ni] = *(const bf16x8*)&sB[row*32 + ((lg ^ (row & 3)) * 8)];
    }
    #pragma unroll
    for (int mi = 0; mi < 4; mi++)
      #pragma unroll
      for (int ni = 0; ni < 4; ni++)
        acc[mi][ni] = __builtin_amdgcn_mfma_f32_16x16x32_bf16(af[mi], bfr[ni], acc[mi][ni], 0, 0, 0);
    __syncthreads();
  }
  #pragma unroll
  for (int mi = 0; mi < 4; mi++){
    int row = m0 + wr*64 + mi*16 + lg*4;
    #pragma unroll
    for (int ni = 0; ni < 4; ni++){
      int col = n0 + wc*64 + ni*16 + lr;
      f32x4 v = acc[mi][ni];
      #pragma unroll
      for (int r = 0; r < 4; r++){
        if (MODE == 0){
          ((u16*)Cv)[(size_t)(row + r)*N + col] = f2bf(v[r]);
        } else if (MODE == 1){
          ((float*)Cv)[(size_t)(row + r)*N + col] = v[r];
        } else {
          int rr = row + r;
          int h = col >> 6, d = col & 63, b = rr >> 11, s = rr & (SEQ-1);
          ((u16*)Cv)[(((size_t)(b*N_HEADS + h))*HEAD_DIM + d)*SEQ + s] = f2bf(v[r]);
        }
      }
    }
  }
}

// ---------- RoPE in place on q and k (bf16) ----------
__global__ void k_rope(u16* __restrict__ q, u16* __restrict__ k, const float2* __restrict__ tab){
  int gid = blockIdx.x * 256 + threadIdx.x;   // MROWS*512
  u16* t = blockIdx.y ? k : q;
  int row = gid >> 9, pidx = gid & 511;
  int h = pidx >> 5, f = pidx & 31;
  int s = row & (SEQ - 1);
  size_t a = (size_t)row * D_MODEL + h*HEAD_DIM + 2*f;
  float e = bf2f(t[a]), o = bf2f(t[a+1]);
  float2 cs = tab[s*32 + f];
  t[a]   = f2bf(e*cs.x - o*cs.y);
  t[a+1] = f2bf(e*cs.y + o*cs.x);
}

// ---------- causal flash attention ----------
// grid (S/64, H, B), 256 thr = 4 waves; wave w owns q rows qt*64+w*16 .. +16
__global__ __launch_bounds__(256) void k_attn(const u16* __restrict__ q, const u16* __restrict__ k,
                                              const u16* __restrict__ vt, u16* __restrict__ ctx){
  __shared__ __align__(16) char pbuf_raw[4*1024];   // per-wave 1KB P scratch
  int lane = threadIdx.x & 63, w = threadIdx.x >> 6;
  int lr = lane & 15, lg = lane >> 4;
  int qt = blockIdx.x, h = blockIdx.y, b = blockIdx.z;
  int qbase = qt*64 + w*16;
  char* pb = pbuf_raw + w*1024;
  const u16* qp = q  + (size_t)(b*SEQ + qbase)*D_MODEL + h*HEAD_DIM;
  const u16* kp = k  + (size_t)(b*SEQ)*D_MODEL + h*HEAD_DIM;
  const u16* vp = vt + (size_t)(b*N_HEADS + h)*HEAD_DIM*SEQ;
  bf16x8 qf[2];
  #pragma unroll
  for (int hf = 0; hf < 2; hf++)
    qf[hf] = *(const bf16x8*)&qp[(size_t)lr*D_MODEL + hf*32 + lg*8];
  f32x4 acc[4] = {};
  float mr[4], ls[4];
  #pragma unroll
  for (int r = 0; r < 4; r++){ mr[r] = -3.0e38f; ls[r] = 0.f; }
  const float scale = 0.125f;       // 1/sqrt(64)
  const float L2E = 1.44269504f;
  for (int j0 = 0; j0 < qbase + 16; j0 += 32){
    f32x4 z = {};
    f32x4 sc[2];
    #pragma unroll
    for (int sub = 0; sub < 2; sub++){
      bf16x8 kf0 = *(const bf16x8*)&kp[(size_t)(j0 + sub*16 + lr)*D_MODEL + lg*8];
      bf16x8 kf1 = *(const bf16x8*)&kp[(size_t)(j0 + sub*16 + lr)*D_MODEL + 32 + lg*8];
      sc[sub] = __builtin_amdgcn_mfma_f32_16x16x32_bf16(qf[0], kf0, z, 0, 0, 0);
      sc[sub] = __builtin_amdgcn_mfma_f32_16x16x32_bf16(qf[1], kf1, sc[sub], 0, 0, 0);
    }
    float v[2][4], pm[4];
    #pragma unroll
    for (int r = 0; r < 4; r++){
      int qrow = qbase + lg*4 + r;
      #pragma unroll
      for (int sub = 0; sub < 2; sub++){
        int key = j0 + sub*16 + lr;
        float xv = sc[sub][r] * scale;
        v[sub][r] = (key <= qrow) ? xv : -3.0e38f;
      }
      pm[r] = fmaxf(v[0][r], v[1][r]);
    }
    #pragma unroll
    for (int off = 1; off < 16; off <<= 1)
      #pragma unroll
      for (int r = 0; r < 4; r++)
        pm[r] = fmaxf(pm[r], __shfl_xor(pm[r], off));
    float p[2][4], rs[4], corr[4];
    #pragma unroll
    for (int r = 0; r < 4; r++){
      float mn = fmaxf(mr[r], pm[r]);
      corr[r] = exp2f((mr[r] - mn) * L2E);
      mr[r] = mn;
      p[0][r] = exp2f((v[0][r] - mn) * L2E);
      p[1][r] = exp2f((v[1][r] - mn) * L2E);
      rs[r] = p[0][r] + p[1][r];
    }
    #pragma unroll
    for (int off = 1; off < 16; off <<= 1)
      #pragma unroll
      for (int r = 0; r < 4; r++)
        rs[r] += __shfl_xor(rs[r], off);
    #pragma unroll
    for (int r = 0; r < 4; r++) ls[r] = ls[r]*corr[r] + rs[r];
    // P (bf16) -> per-wave LDS, XOR-swizzled (write D-layout, read A-layout)
    #pragma unroll
    for (int sub = 0; sub < 2; sub++)
      #pragma unroll
      for (int r = 0; r < 4; r++)
        *(u16*)(pb + (lg*4 + r)*64 + (((sub*16 + lr)*2) ^ (r << 4))) = f2bf(p[sub][r]);
    bf16x8 pa = *(const bf16x8*)(pb + lr*64 + ((lg*16) ^ ((lr & 3) << 4)));
    #pragma unroll
    for (int nb = 0; nb < 4; nb++){
      bf16x8 vf = *(const bf16x8*)&vp[(size_t)(nb*16 + lr)*SEQ + j0 + lg*8];
      f32x4 a = acc[nb];
      #pragma unroll
      for (int r = 0; r < 4; r++) a[r] *= corr[r];
      acc[nb] = __builtin_amdgcn_mfma_f32_16x16x32_bf16(pa, vf, a, 0, 0, 0);
    }
  }
  #pragma unroll
  for (int r = 0; r < 4; r++) ls[r] = 1.0f / ls[r];
  u16* cp = ctx + (size_t)(b*SEQ + qbase)*D_MODEL + h*HEAD_DIM;
  #pragma unroll
  for (int nb = 0; nb < 4; nb++)
    #pragma unroll
    for (int r = 0; r < 4; r++)
      cp[(size_t)(lg*4 + r)*D_MODEL + nb*16 + lr] = f2bf(acc[nb][r] * ls[r]);
}

extern "C" void kernel_launch(void* const* d_in, const int* in_sizes, int n_in,
                              void* d_out, int out_size, void* d_ws, size_t ws_size,
                              hipStream_t stream){
  const float* x  = (const float*)d_in[0];
  const int*  pos = (const int*)d_in[1];
  const float* Wq = (const float*)d_in[2];
  const float* Wk = (const float*)d_in[3];
  const float* Wv = (const float*)d_in[4];
  const float* Wo = (const float*)d_in[5];
  float* out = (float*)d_out;
  char* ws = (char*)d_ws;
  // workspace layout (bytes)
  u16* xb   = (u16*)(ws);                    // 16 MB  x bf16 (reused as ctx later)
  u16* wt   = (u16*)(ws + 16777216);         // 8 MB   Wt q,k,v,o transposed bf16
  u16* qb   = (u16*)(ws + 25165824);         // 16 MB
  u16* kb   = (u16*)(ws + 41943040);         // 16 MB
  u16* vtb  = (u16*)(ws + 58720256);         // 16 MB  V transposed [b][h][d][s]
  float2* tab = (float2*)(ws + 75497472);    // 512 KB rope table
  u16* ctxb = xb;                            // reuse x buffer for ctx

  k_cvt_x<<<(MROWS*D_MODEL/4)/256, 256, 0, stream>>>(x, xb, MROWS*D_MODEL/4);
  k_transpose_w<<<dim3(32,32,4), dim3(32,8), 0, stream>>>(Wq, Wk, Wv, Wo, wt);
  k_rope_tab<<<(SEQ*32)/256, 256, 0, stream>>>(pos, tab);
  k_gemm<0><<<dim3(64,8), 256, 0, stream>>>(xb, wt,           qb);
  k_gemm<0><<<dim3(64,8), 256, 0, stream>>>(xb, wt + 1048576, kb);
  k_gemm<2><<<dim3(64,8), 256, 0, stream>>>(xb, wt + 2097152, vtb);
  k_rope<<<dim3((MROWS*512)/256, 2), 256, 0, stream>>>(qb, kb, tab);
  k_attn<<<dim3(SEQ/64, N_HEADS, BATCH), 256, 0, stream>>>(qb, kb, vtb, ctxb);
  k_gemm<1><<<dim3(64,8), 256, 0, stream>>>(ctxb, wt + 3145728, out);
}

// Round 2
// 268.891 us; speedup vs baseline: 2.1949x; 2.1949x over previous
//
#include <hip/hip_runtime.h>

typedef unsigned short u16;
typedef unsigned int   u32;
typedef __bf16  bf16x8 __attribute__((ext_vector_type(8)));
typedef float   f32x4  __attribute__((ext_vector_type(4)));
typedef float   f32x16 __attribute__((ext_vector_type(16)));
typedef u16     u16x4  __attribute__((ext_vector_type(4)));
typedef u16     u16x8  __attribute__((ext_vector_type(8)));
typedef u32     u32x4  __attribute__((ext_vector_type(4)));

#define D_MODEL 1024
#define N_HEADS 16
#define HEAD_DIM 64
#define BATCH 4
#define SEQ 2048
#define MROWS (BATCH*SEQ)

__device__ __forceinline__ u16 f2bf(float f){
  unsigned u = __builtin_bit_cast(unsigned, f);
  u += 0x7fffu + ((u >> 16) & 1u);
  return (u16)(u >> 16);
}
__device__ __forceinline__ float bf2f(u16 h){
  unsigned u = ((unsigned)h) << 16;
  return __builtin_bit_cast(float, u);
}
__device__ __forceinline__ u32 pkbf(float a, float b){
  return (u32)f2bf(a) | ((u32)f2bf(b) << 16);
}
__device__ __forceinline__ void gload_lds16(const u16* g, u16* l){
  __builtin_amdgcn_global_load_lds((const __attribute__((address_space(1))) void*)g,
                                   (__attribute__((address_space(3))) void*)l, 16, 0, 0);
}

// ---------- x fp32 -> bf16 ----------
__global__ void k_cvt_x(const float* __restrict__ x, u16* __restrict__ xb, int n4){
  int i = blockIdx.x * 256 + threadIdx.x;
  if (i >= n4) return;
  float4 v = reinterpret_cast<const float4*>(x)[i];
  u16x4 o;
  o.x = f2bf(v.x); o.y = f2bf(v.y); o.z = f2bf(v.z); o.w = f2bf(v.w);
  *reinterpret_cast<u16x4*>(xb + (size_t)i * 4) = o;
}

// ---------- W fp32 [k][n] -> bf16 Wt [n][k] ----------
__global__ void k_transpose_w(const float* __restrict__ Wq, const float* __restrict__ Wk,
                              const float* __restrict__ Wv, const float* __restrict__ Wo,
                              u16* __restrict__ wt){
  __shared__ float t[32][33];
  int z = blockIdx.z;
  const float* W = (z==0)?Wq:(z==1)?Wk:(z==2)?Wv:Wo;
  u16* O = wt + (size_t)z * (D_MODEL*(size_t)D_MODEL);
  int n0 = blockIdx.x*32, k0 = blockIdx.y*32;
  int tx = threadIdx.x, ty = threadIdx.y;
  #pragma unroll
  for (int i = ty; i < 32; i += 8) t[i][tx] = W[(size_t)(k0+i)*D_MODEL + n0 + tx];
  __syncthreads();
  #pragma unroll
  for (int i = ty; i < 32; i += 8) O[(size_t)(n0+i)*D_MODEL + k0 + tx] = f2bf(t[tx][i]);
}

// ---------- RoPE cos/sin table ----------
__global__ void k_rope_tab(const int* __restrict__ pos, float2* __restrict__ tab){
  int i = blockIdx.x * 256 + threadIdx.x;          // SEQ*32 threads
  int s = i >> 5, f = i & 31;
  float inv = exp2f(-(float)f * (13.287712379549449f / 32.0f)); // theta^(-f/32)
  float a = (float)pos[s] * inv;
  float sn, cs;
  sincosf(a, &sn, &cs);
  tab[i] = make_float2(cs, sn);
}

// ---------- GEMM (m97-style 128x128, BK=32) ----------
// MODE 0: bf16 out row-major. MODE 1: f32 out row-major. MODE 2: bf16 out Vt[b][h][d][s].
template<int MODE>
__global__ __launch_bounds__(256) void k_gemm(const u16* __restrict__ A, const u16* __restrict__ Bt,
                                              void* __restrict__ Cv){
  __shared__ u16 sA[128*32];
  __shared__ u16 sB[128*32];
  const int K = 1024, N = 1024;
  int tid = threadIdx.x, lane = tid & 63, w = tid >> 6;
  int lr = lane & 15, lg = lane >> 4;
  int m0 = blockIdx.x * 128, n0 = blockIdx.y * 128;
  int wr = w >> 1, wc = w & 1;
  int srow = lane >> 2;
  int schunk = (lane & 3) ^ (srow & 3);
  const u16* ga0 = A  + (size_t)(m0 + w*32 + srow)*K + schunk*8;
  const u16* gb0 = Bt + (size_t)(n0 + w*32 + srow)*K + schunk*8;
  u16* la = sA + (size_t)w*32*32;
  u16* lb = sB + (size_t)w*32*32;
  f32x4 acc[4][4] = {};
  for (int k0 = 0; k0 < K; k0 += 32){
    gload_lds16(ga0 + k0,        la);
    gload_lds16(ga0 + 16*K + k0, la + 16*32);
    gload_lds16(gb0 + k0,        lb);
    gload_lds16(gb0 + 16*K + k0, lb + 16*32);
    __syncthreads();
    bf16x8 af[4], bfr[4];
    #pragma unroll
    for (int mi = 0; mi < 4; mi++){
      int row = wr*64 + mi*16 + lr;
      af[mi] = *(const bf16x8*)&sA[row*32 + ((lg ^ (row & 3)) * 8)];
    }
    #pragma unroll
    for (int ni = 0; ni < 4; ni++){
      int row = wc*64 + ni*16 + lr;
      bfr[ni] = *(const bf16x8*)&sB[row*32 + ((lg ^ (row & 3)) * 8)];
    }
    #pragma unroll
    for (int mi = 0; mi < 4; mi++)
      #pragma unroll
      for (int ni = 0; ni < 4; ni++)
        acc[mi][ni] = __builtin_amdgcn_mfma_f32_16x16x32_bf16(af[mi], bfr[ni], acc[mi][ni], 0, 0, 0);
    __syncthreads();
  }
  #pragma unroll
  for (int mi = 0; mi < 4; mi++){
    int row = m0 + wr*64 + mi*16 + lg*4;
    #pragma unroll
    for (int ni = 0; ni < 4; ni++){
      int col = n0 + wc*64 + ni*16 + lr;
      f32x4 v = acc[mi][ni];
      #pragma unroll
      for (int r = 0; r < 4; r++){
        if (MODE == 0){
          ((u16*)Cv)[(size_t)(row + r)*N + col] = f2bf(v[r]);
        } else if (MODE == 1){
          ((float*)Cv)[(size_t)(row + r)*N + col] = v[r];
        } else {
          int rr = row + r;
          int h = col >> 6, d = col & 63, b = rr >> 11, s = rr & (SEQ-1);
          ((u16*)Cv)[(((size_t)(b*N_HEADS + h))*HEAD_DIM + d)*SEQ + s] = f2bf(v[r]);
        }
      }
    }
  }
}

// ---------- RoPE in place; q additionally scaled by 1/sqrt(Dk)*log2(e) ----------
__global__ void k_rope(u16* __restrict__ q, u16* __restrict__ k, const float2* __restrict__ tab){
  int gid = blockIdx.x * 256 + threadIdx.x;   // MROWS*512
  u16* t = blockIdx.y ? k : q;
  float sc = blockIdx.y ? 1.0f : 0.18033688011112042f;  // 0.125 * log2(e)
  int row = gid >> 9, pidx = gid & 511;
  int h = pidx >> 5, f = pidx & 31;
  int s = row & (SEQ - 1);
  size_t a = (size_t)row * D_MODEL + h*HEAD_DIM + 2*f;
  float e = bf2f(t[a]), o = bf2f(t[a+1]);
  float2 cs = tab[s*32 + f];
  t[a]   = f2bf((e*cs.x - o*cs.y) * sc);
  t[a+1] = f2bf((e*cs.y + o*cs.x) * sc);
}

// ---------- causal flash attention: swapped-operand 32x32 ----------
// grid 512 blocks x 256 thr (4 waves). Block B: bh = B>>3; wave w: p = (B&7)*4+w.
// Wave processes q-tiles {p, 63-p} (32 rows each) => uniform 65 kv-iters.
// QK^T: mfma(K,Q) -> S[k][q], col=lane&31=q. PV: mfma(Vt,P) -> acc[d][q], col=q.
__global__ __launch_bounds__(256) void k_attn(const u16* __restrict__ q, const u16* __restrict__ k,
                                              const u16* __restrict__ vt, u16* __restrict__ ctx){
  __shared__ u16 tp[4][2048];                 // per-wave 4KB transpose buffer
  const int lane = threadIdx.x & 63, w = threadIdx.x >> 6;
  const int lq = lane & 31, hl = lane >> 5;
  const int bh = blockIdx.x >> 3;
  const int b = bh >> 4, h = bh & 15;
  const int p = (blockIdx.x & 7) * 4 + w;     // 0..31
  const u16* qbase = q  + (size_t)(b*SEQ)*D_MODEL + h*HEAD_DIM;
  const u16* kbase = k  + (size_t)(b*SEQ)*D_MODEL + h*HEAD_DIM;
  const u16* vbase = vt + (size_t)bh*HEAD_DIM*SEQ;
  u16* tb = tp[w];

  for (int pass = 0; pass < 2; ++pass){
    const int qi = pass ? 63 - p : p;
    const int q0 = qi * 32;
    const u16* qr_ = &qbase[(size_t)(q0 + lq)*D_MODEL + hl*8];
    bf16x8 qf0 = *(const bf16x8*)&qr_[0];
    bf16x8 qf1 = *(const bf16x8*)&qr_[16];
    bf16x8 qf2 = *(const bf16x8*)&qr_[32];
    bf16x8 qf3 = *(const bf16x8*)&qr_[48];
    f32x16 acc0 = {}, acc1 = {};
    float m = -3.0e38f, l = 0.f;

    for (int j0 = 0; j0 <= q0; j0 += 32){
      const u16* kr = &kbase[(size_t)(j0 + lq)*D_MODEL + hl*8];
      bf16x8 kf0 = *(const bf16x8*)&kr[0];
      bf16x8 kf1 = *(const bf16x8*)&kr[16];
      bf16x8 kf2 = *(const bf16x8*)&kr[32];
      bf16x8 kf3 = *(const bf16x8*)&kr[48];
      const u16* vr = &vbase[(size_t)lq*SEQ + j0 + hl*8];
      bf16x8 vf00 = *(const bf16x8*)&vr[0];
      bf16x8 vf10 = *(const bf16x8*)&vr[16];
      bf16x8 vf01 = *(const bf16x8*)&vr[32*SEQ];
      bf16x8 vf11 = *(const bf16x8*)&vr[32*SEQ + 16];

      f32x16 S = {};
      S = __builtin_amdgcn_mfma_f32_32x32x16_bf16(kf0, qf0, S, 0, 0, 0);
      S = __builtin_amdgcn_mfma_f32_32x32x16_bf16(kf1, qf1, S, 0, 0, 0);
      S = __builtin_amdgcn_mfma_f32_32x32x16_bf16(kf2, qf2, S, 0, 0, 0);
      S = __builtin_amdgcn_mfma_f32_32x32x16_bf16(kf3, qf3, S, 0, 0, 0);

      if (j0 == q0){                          // diagonal tile: mask k > q
        #pragma unroll
        for (int r = 0; r < 16; ++r){
          int kk = (r & 3) + 8*(r >> 2) + 4*hl;
          if (kk > lq) S[r] = -3.0e38f;
        }
      }
      // per-q (per-lane-column) max, log2 domain (scale folded into q)
      float a0 = fmaxf(fmaxf(S[0],S[1]),  fmaxf(S[2],S[3]));
      float a1 = fmaxf(fmaxf(S[4],S[5]),  fmaxf(S[6],S[7]));
      float a2 = fmaxf(fmaxf(S[8],S[9]),  fmaxf(S[10],S[11]));
      float a3 = fmaxf(fmaxf(S[12],S[13]),fmaxf(S[14],S[15]));
      float pm = fmaxf(fmaxf(a0,a1), fmaxf(a2,a3));
      pm = fmaxf(pm, __shfl_xor(pm, 32));
      if (__any(pm > m + 8.f)){               // defer-max (T13)
        float mn = fmaxf(m, pm);
        float cr = __builtin_amdgcn_exp2f(m - mn);
        l *= cr;
        #pragma unroll
        for (int r = 0; r < 16; ++r){ acc0[r] *= cr; acc1[r] *= cr; }
        m = mn;
      }
      f32x16 P;
      #pragma unroll
      for (int r = 0; r < 16; ++r) P[r] = __builtin_amdgcn_exp2f(S[r] - m);
      float s0_ = (P[0]+P[1]) + (P[2]+P[3]);
      float s1_ = (P[4]+P[5]) + (P[6]+P[7]);
      float s2_ = (P[8]+P[9]) + (P[10]+P[11]);
      float s3_ = (P[12]+P[13]) + (P[14]+P[15]);
      float rs = (s0_+s1_) + (s2_+s3_);
      rs += __shfl_xor(rs, 32);
      l += rs;
      // pack P -> bf16 pairs; group g holds k=4g..4g+3 (pre-exchange, local hi=hl)
      u32 g0a = pkbf(P[0], P[1]),  g0b = pkbf(P[2], P[3]);
      u32 g1a = pkbf(P[4], P[5]),  g1b = pkbf(P[6], P[7]);
      u32 g2a = pkbf(P[8], P[9]),  g2b = pkbf(P[10],P[11]);
      u32 g3a = pkbf(P[12],P[13]), g3b = pkbf(P[14],P[15]);
      // exchange with lane^32: I need group (2t+hl) from BOTH halves; partner needs (2t+hl^1) from me.
      u32 s0a = hl ? g0a : g1a, s0b = hl ? g0b : g1b;          // send for t=0
      u32 e0a = (u32)__shfl_xor((int)s0a, 32), e0b = (u32)__shfl_xor((int)s0b, 32);
      u32 m0a = hl ? g1a : g0a, m0b = hl ? g1b : g0b;          // mine for t=0
      u32 s1a = hl ? g2a : g3a, s1b = hl ? g2b : g3b;          // send for t=1
      u32 e1a = (u32)__shfl_xor((int)s1a, 32), e1b = (u32)__shfl_xor((int)s1b, 32);
      u32 m1a = hl ? g3a : g2a, m1b = hl ? g3b : g2b;          // mine for t=1
      // slots 0..3 from hi=0 source, 4..7 from hi=1 source
      u32x4 A0 = { hl ? e0a : m0a, hl ? e0b : m0b, hl ? m0a : e0a, hl ? m0b : e0b };
      u32x4 A1 = { hl ? e1a : m1a, hl ? e1b : m1b, hl ? m1a : e1a, hl ? m1b : e1b };
      bf16x8 pa0 = __builtin_bit_cast(bf16x8, A0);
      bf16x8 pa1 = __builtin_bit_cast(bf16x8, A1);
      acc0 = __builtin_amdgcn_mfma_f32_32x32x16_bf16(vf00, pa0, acc0, 0, 0, 0);
      acc0 = __builtin_amdgcn_mfma_f32_32x32x16_bf16(vf10, pa1, acc0, 0, 0, 0);
      acc1 = __builtin_amdgcn_mfma_f32_32x32x16_bf16(vf01, pa0, acc1, 0, 0, 0);
      acc1 = __builtin_amdgcn_mfma_f32_32x32x16_bf16(vf11, pa1, acc1, 0, 0, 0);
    }
    // epilogue: normalize, transpose via swizzled LDS, coalesced 16B stores
    float inv = __builtin_amdgcn_rcpf(l);
    char* tbc = (char*)tb;
    #pragma unroll
    for (int r = 0; r < 16; ++r){
      int d0 = (r & 3) + 8*(r >> 2) + 4*hl;
      *(u16*)(tbc + lq*128 + ((2*d0)      ^ ((lq & 7) << 4))) = f2bf(acc0[r] * inv);
      *(u16*)(tbc + lq*128 + ((2*(d0+32)) ^ ((lq & 7) << 4))) = f2bf(acc1[r] * inv);
    }
    int qr2 = lane >> 1, chb = (lane & 1) * 4;
    u16* cp = ctx + (size_t)(b*SEQ + q0 + qr2)*D_MODEL + h*HEAD_DIM;
    #pragma unroll
    for (int i = 0; i < 4; ++i){
      int ch = chb + i;
      u16x8 vv = *(const u16x8*)(tbc + qr2*128 + 16*(ch ^ (qr2 & 7)));
      *(u16x8*)&cp[ch*8] = vv;
    }
  }
}

extern "C" void kernel_launch(void* const* d_in, const int* in_sizes, int n_in,
                              void* d_out, int out_size, void* d_ws, size_t ws_size,
                              hipStream_t stream){
  const float* x  = (const float*)d_in[0];
  const int*  pos = (const int*)d_in[1];
  const float* Wq = (const float*)d_in[2];
  const float* Wk = (const float*)d_in[3];
  const float* Wv = (const float*)d_in[4];
  const float* Wo = (const float*)d_in[5];
  float* out = (float*)d_out;
  char* ws = (char*)d_ws;
  u16* xb   = (u16*)(ws);                    // 16 MB  x bf16 (reused as ctx later)
  u16* wt   = (u16*)(ws + 16777216);         // 8 MB   Wt q,k,v,o transposed bf16
  u16* qb   = (u16*)(ws + 25165824);         // 16 MB
  u16* kb   = (u16*)(ws + 41943040);         // 16 MB
  u16* vtb  = (u16*)(ws + 58720256);         // 16 MB  V transposed [b][h][d][s]
  float2* tab = (float2*)(ws + 75497472);    // 512 KB rope table
  u16* ctxb = xb;

  k_cvt_x<<<(MROWS*D_MODEL/4)/256, 256, 0, stream>>>(x, xb, MROWS*D_MODEL/4);
  k_transpose_w<<<dim3(32,32,4), dim3(32,8), 0, stream>>>(Wq, Wk, Wv, Wo, wt);
  k_rope_tab<<<(SEQ*32)/256, 256, 0, stream>>>(pos, tab);
  k_gemm<0><<<dim3(64,8), 256, 0, stream>>>(xb, wt,           qb);
  k_gemm<0><<<dim3(64,8), 256, 0, stream>>>(xb, wt + 1048576, kb);
  k_gemm<2><<<dim3(64,8), 256, 0, stream>>>(xb, wt + 2097152, vtb);
  k_rope<<<dim3((MROWS*512)/256, 2), 256, 0, stream>>>(qb, kb, tab);
  k_attn<<<dim3(512), 256, 0, stream>>>(qb, kb, vtb, ctxb);
  k_gemm<1><<<dim3(64,8), 256, 0, stream>>>(ctxb, wt + 3145728, out);
}

// Round 3
// 255.628 us; speedup vs baseline: 2.3088x; 1.0519x over previous
//
#include <hip/hip_runtime.h>

typedef unsigned short u16;
typedef unsigned int   u32;
typedef __bf16  bf16x8 __attribute__((ext_vector_type(8)));
typedef float   f32x4  __attribute__((ext_vector_type(4)));
typedef float   f32x16 __attribute__((ext_vector_type(16)));
typedef u16     u16x4  __attribute__((ext_vector_type(4)));
typedef u16     u16x8  __attribute__((ext_vector_type(8)));
typedef u32     u32x4  __attribute__((ext_vector_type(4)));

#define D_MODEL 1024
#define N_HEADS 16
#define HEAD_DIM 64
#define BATCH 4
#define SEQ 2048
#define MROWS (BATCH*SEQ)

__device__ __forceinline__ u16 f2bf(float f){
  unsigned u = __builtin_bit_cast(unsigned, f);
  u += 0x7fffu + ((u >> 16) & 1u);
  return (u16)(u >> 16);
}
__device__ __forceinline__ float bf2f(u16 h){
  unsigned u = ((unsigned)h) << 16;
  return __builtin_bit_cast(float, u);
}
__device__ __forceinline__ u32 cvtpk(float a, float b){
  u32 r; asm("v_cvt_pk_bf16_f32 %0, %1, %2" : "=v"(r) : "v"(a), "v"(b)); return r;
}
__device__ __forceinline__ void gload_lds16(const u16* g, u16* l){
  __builtin_amdgcn_global_load_lds((const __attribute__((address_space(1))) void*)g,
                                   (__attribute__((address_space(3))) void*)l, 16, 0, 0);
}

// ---------- x fp32 -> bf16 ----------
__global__ void k_cvt_x(const float* __restrict__ x, u16* __restrict__ xb, int n4){
  int i = blockIdx.x * 256 + threadIdx.x;
  if (i >= n4) return;
  float4 v = reinterpret_cast<const float4*>(x)[i];
  u16x4 o;
  o.x = f2bf(v.x); o.y = f2bf(v.y); o.z = f2bf(v.z); o.w = f2bf(v.w);
  *reinterpret_cast<u16x4*>(xb + (size_t)i * 4) = o;
}

// ---------- W fp32 [k][n] -> bf16 Wt [n][k] ----------
__global__ void k_transpose_w(const float* __restrict__ Wq, const float* __restrict__ Wk,
                              const float* __restrict__ Wv, const float* __restrict__ Wo,
                              u16* __restrict__ wt){
  __shared__ float t[32][33];
  int z = blockIdx.z;
  const float* W = (z==0)?Wq:(z==1)?Wk:(z==2)?Wv:Wo;
  u16* O = wt + (size_t)z * (D_MODEL*(size_t)D_MODEL);
  int n0 = blockIdx.x*32, k0 = blockIdx.y*32;
  int tx = threadIdx.x, ty = threadIdx.y;
  #pragma unroll
  for (int i = ty; i < 32; i += 8) t[i][tx] = W[(size_t)(k0+i)*D_MODEL + n0 + tx];
  __syncthreads();
  #pragma unroll
  for (int i = ty; i < 32; i += 8) O[(size_t)(n0+i)*D_MODEL + k0 + tx] = f2bf(t[tx][i]);
}

// ---------- RoPE cos/sin table ----------
__global__ void k_rope_tab(const int* __restrict__ pos, float2* __restrict__ tab){
  int i = blockIdx.x * 256 + threadIdx.x;          // SEQ*32 threads
  int s = i >> 5, f = i & 31;
  float inv = exp2f(-(float)f * (13.287712379549449f / 32.0f)); // theta^(-f/32)
  float a = (float)pos[s] * inv;
  float sn, cs;
  sincosf(a, &sn, &cs);
  tab[i] = make_float2(cs, sn);
}

// ---------- fused QKV GEMM: [8192][1024] @ wt[3072][1024]^T, RoPE in epilogue ----------
// q -> row-major bf16 [8192][1024] (scaled by 0.125*log2e)
// k -> kbh [b][h][s][64] bf16 (rope'd)
// v -> vt2 [b][h][s/16][d][16] bf16
__global__ __launch_bounds__(256) void k_gemm_qkv(const u16* __restrict__ A, const u16* __restrict__ Bt,
                                                  const float2* __restrict__ tab,
                                                  u16* __restrict__ qout, u16* __restrict__ kout,
                                                  u16* __restrict__ vout){
  __shared__ u16 sA[128*32];
  __shared__ u16 sB[128*32];
  const int K = 1024;
  int tid = threadIdx.x, lane = tid & 63, w = tid >> 6;
  int lr = lane & 15, lg = lane >> 4;
  int m0 = blockIdx.x * 128, n0 = blockIdx.y * 128;
  int wr = w >> 1, wc = w & 1;
  int srow = lane >> 2;
  int schunk = (lane & 3) ^ (srow & 3);
  const u16* ga0 = A  + (size_t)(m0 + w*32 + srow)*K + schunk*8;
  const u16* gb0 = Bt + (size_t)(n0 + w*32 + srow)*K + schunk*8;
  u16* la = sA + (size_t)w*32*32;
  u16* lb = sB + (size_t)w*32*32;
  f32x4 acc[4][4] = {};
  for (int k0 = 0; k0 < K; k0 += 32){
    gload_lds16(ga0 + k0,        la);
    gload_lds16(ga0 + 16*K + k0, la + 16*32);
    gload_lds16(gb0 + k0,        lb);
    gload_lds16(gb0 + 16*K + k0, lb + 16*32);
    __syncthreads();
    bf16x8 af[4], bfr[4];
    #pragma unroll
    for (int mi = 0; mi < 4; mi++){
      int row = wr*64 + mi*16 + lr;
      af[mi] = *(const bf16x8*)&sA[row*32 + ((lg ^ (row & 3)) * 8)];
    }
    #pragma unroll
    for (int ni = 0; ni < 4; ni++){
      int row = wc*64 + ni*16 + lr;
      bfr[ni] = *(const bf16x8*)&sB[row*32 + ((lg ^ (row & 3)) * 8)];
    }
    #pragma unroll
    for (int mi = 0; mi < 4; mi++)
      #pragma unroll
      for (int ni = 0; ni < 4; ni++)
        acc[mi][ni] = __builtin_amdgcn_mfma_f32_16x16x32_bf16(af[mi], bfr[ni], acc[mi][ni], 0, 0, 0);
    __syncthreads();
  }
  const int which = n0 >> 10;                 // 0=q 1=k 2=v
  #pragma unroll
  for (int mi = 0; mi < 4; mi++){
    int row = m0 + wr*64 + mi*16 + lg*4;
    #pragma unroll
    for (int ni = 0; ni < 4; ni++){
      int col = n0 + wc*64 + ni*16 + lr;
      int cm = col & 1023;
      int hh = cm >> 6, d = cm & 63;
      f32x4 vv = acc[mi][ni];
      #pragma unroll
      for (int r = 0; r < 4; r++){
        int rr = row + r;
        int bb = rr >> 11, s = rr & (SEQ-1);
        float val = vv[r];
        if (which < 2){
          float partner = __shfl_xor(val, 1);
          float2 cs = tab[s*32 + (d >> 1)];
          float o = (d & 1) ? (partner*cs.y + val*cs.x) : (val*cs.x - partner*cs.y);
          if (which == 0){
            o *= 0.18033688011112042f;        // 0.125 * log2(e)
            qout[(size_t)rr*1024 + cm] = f2bf(o);
          } else {
            kout[(((size_t)(bb*N_HEADS + hh))*SEQ + s)*64 + d] = f2bf(o);
          }
        } else {
          vout[(((size_t)(bb*N_HEADS + hh))*(SEQ/16) + (s >> 4))*1024 + d*16 + (s & 15)] = f2bf(val);
        }
      }
    }
  }
}

// ---------- Wo GEMM: out f32 = ctx(bf16)[8192][1024] @ wt_o[1024][1024]^T ----------
__global__ __launch_bounds__(256) void k_gemm_wo(const u16* __restrict__ A, const u16* __restrict__ Bt,
                                                 float* __restrict__ Cv){
  __shared__ u16 sA[128*32];
  __shared__ u16 sB[128*32];
  const int K = 1024, N = 1024;
  int tid = threadIdx.x, lane = tid & 63, w = tid >> 6;
  int lr = lane & 15, lg = lane >> 4;
  int m0 = blockIdx.x * 128, n0 = blockIdx.y * 128;
  int wr = w >> 1, wc = w & 1;
  int srow = lane >> 2;
  int schunk = (lane & 3) ^ (srow & 3);
  const u16* ga0 = A  + (size_t)(m0 + w*32 + srow)*K + schunk*8;
  const u16* gb0 = Bt + (size_t)(n0 + w*32 + srow)*K + schunk*8;
  u16* la = sA + (size_t)w*32*32;
  u16* lb = sB + (size_t)w*32*32;
  f32x4 acc[4][4] = {};
  for (int k0 = 0; k0 < K; k0 += 32){
    gload_lds16(ga0 + k0,        la);
    gload_lds16(ga0 + 16*K + k0, la + 16*32);
    gload_lds16(gb0 + k0,        lb);
    gload_lds16(gb0 + 16*K + k0, lb + 16*32);
    __syncthreads();
    bf16x8 af[4], bfr[4];
    #pragma unroll
    for (int mi = 0; mi < 4; mi++){
      int row = wr*64 + mi*16 + lr;
      af[mi] = *(const bf16x8*)&sA[row*32 + ((lg ^ (row & 3)) * 8)];
    }
    #pragma unroll
    for (int ni = 0; ni < 4; ni++){
      int row = wc*64 + ni*16 + lr;
      bfr[ni] = *(const bf16x8*)&sB[row*32 + ((lg ^ (row & 3)) * 8)];
    }
    #pragma unroll
    for (int mi = 0; mi < 4; mi++)
      #pragma unroll
      for (int ni = 0; ni < 4; ni++)
        acc[mi][ni] = __builtin_amdgcn_mfma_f32_16x16x32_bf16(af[mi], bfr[ni], acc[mi][ni], 0, 0, 0);
    __syncthreads();
  }
  #pragma unroll
  for (int mi = 0; mi < 4; mi++){
    int row = m0 + wr*64 + mi*16 + lg*4;
    #pragma unroll
    for (int ni = 0; ni < 4; ni++){
      int col = n0 + wc*64 + ni*16 + lr;
      f32x4 v = acc[mi][ni];
      #pragma unroll
      for (int r = 0; r < 4; r++)
        Cv[(size_t)(row + r)*N + col] = v[r];
    }
  }
}

// ---------- causal flash attention: swapped-operand 32x32, coalesced K/V layouts ----------
// grid 1024 blocks x 256 thr (4 waves). Block B: bh = B&63, g = B>>6 (0..15).
// Tile set {g, 63-g, 31-g, 32+g} (sum=130 iters), rotated by (w + B>>8)&3 so each
// SIMD's resident waves sum to exactly 130 iters.
__global__ __launch_bounds__(256) void k_attn(const u16* __restrict__ q, const u16* __restrict__ k2,
                                              const u16* __restrict__ v2, u16* __restrict__ ctx){
  __shared__ u16 tp[4][2048];                 // per-wave 4KB transpose buffer
  const int lane = threadIdx.x & 63, w = threadIdx.x >> 6;
  const int lq = lane & 31, hl = lane >> 5;
  const int B = blockIdx.x;
  const int bh = B & 63, g = B >> 6;
  const int b = bh >> 4, h = bh & 15;
  const int sel = (w + (B >> 8)) & 3;
  int qi = (sel == 0) ? g : (sel == 1) ? (63 - g) : (sel == 2) ? (31 - g) : (32 + g);
  const int q0 = qi * 32;
  const u16* kbase = k2 + (size_t)bh*SEQ*64;
  const u16* vbase = v2 + (size_t)bh*(SEQ/16)*1024;
  u16* tb = tp[w];

  const u16* qr_ = &q[(size_t)(b*SEQ + q0 + lq)*D_MODEL + h*HEAD_DIM + hl*8];
  bf16x8 qf0 = *(const bf16x8*)&qr_[0];
  bf16x8 qf1 = *(const bf16x8*)&qr_[16];
  bf16x8 qf2 = *(const bf16x8*)&qr_[32];
  bf16x8 qf3 = *(const bf16x8*)&qr_[48];
  f32x16 acc0 = {}, acc1 = {};
  float m = -3.0e38f, l = 0.f;

  for (int j0 = 0; j0 <= q0; j0 += 32){
    const u16* kr = &kbase[(size_t)(j0 + lq)*64 + hl*8];
    bf16x8 kf0 = *(const bf16x8*)&kr[0];
    bf16x8 kf1 = *(const bf16x8*)&kr[16];
    bf16x8 kf2 = *(const bf16x8*)&kr[32];
    bf16x8 kf3 = *(const bf16x8*)&kr[48];
    const u16* vr = &vbase[(size_t)(j0 >> 4)*1024 + lq*16 + hl*8];
    bf16x8 vf00 = *(const bf16x8*)&vr[0];
    bf16x8 vf10 = *(const bf16x8*)&vr[1024];
    bf16x8 vf01 = *(const bf16x8*)&vr[512];
    bf16x8 vf11 = *(const bf16x8*)&vr[1536];

    f32x16 S = {};
    S = __builtin_amdgcn_mfma_f32_32x32x16_bf16(kf0, qf0, S, 0, 0, 0);
    S = __builtin_amdgcn_mfma_f32_32x32x16_bf16(kf1, qf1, S, 0, 0, 0);
    S = __builtin_amdgcn_mfma_f32_32x32x16_bf16(kf2, qf2, S, 0, 0, 0);
    S = __builtin_amdgcn_mfma_f32_32x32x16_bf16(kf3, qf3, S, 0, 0, 0);

    if (j0 == q0){                            // diagonal tile: mask k > q
      #pragma unroll
      for (int r = 0; r < 16; ++r){
        int kk = (r & 3) + 8*(r >> 2) + 4*hl;
        if (kk > lq) S[r] = -3.0e38f;
      }
    }
    float a0 = fmaxf(fmaxf(S[0],S[1]),  fmaxf(S[2],S[3]));
    float a1 = fmaxf(fmaxf(S[4],S[5]),  fmaxf(S[6],S[7]));
    float a2 = fmaxf(fmaxf(S[8],S[9]),  fmaxf(S[10],S[11]));
    float a3 = fmaxf(fmaxf(S[12],S[13]),fmaxf(S[14],S[15]));
    float pm = fmaxf(fmaxf(a0,a1), fmaxf(a2,a3));
    pm = fmaxf(pm, __shfl_xor(pm, 32));
    if (__any(pm > m + 8.f)){                 // defer-max (T13)
      float mn = fmaxf(m, pm);
      float cr = __builtin_amdgcn_exp2f(m - mn);
      l *= cr;
      #pragma unroll
      for (int r = 0; r < 16; ++r){ acc0[r] *= cr; acc1[r] *= cr; }
      m = mn;
    }
    f32x16 P;
    #pragma unroll
    for (int r = 0; r < 16; ++r) P[r] = __builtin_amdgcn_exp2f(S[r] - m);
    float s0_ = (P[0]+P[1]) + (P[2]+P[3]);
    float s1_ = (P[4]+P[5]) + (P[6]+P[7]);
    float s2_ = (P[8]+P[9]) + (P[10]+P[11]);
    float s3_ = (P[12]+P[13]) + (P[14]+P[15]);
    float rs = (s0_+s1_) + (s2_+s3_);
    rs += __shfl_xor(rs, 32);
    l += rs;
    // pack P -> bf16 pairs (cvt_pk); group g holds k=4g..4g+3 (pre-exchange, local hi=hl)
    u32 g0a = cvtpk(P[0], P[1]),  g0b = cvtpk(P[2], P[3]);
    u32 g1a = cvtpk(P[4], P[5]),  g1b = cvtpk(P[6], P[7]);
    u32 g2a = cvtpk(P[8], P[9]),  g2b = cvtpk(P[10],P[11]);
    u32 g3a = cvtpk(P[12],P[13]), g3b = cvtpk(P[14],P[15]);
    u32 s0a = hl ? g0a : g1a, s0b = hl ? g0b : g1b;
    u32 e0a = (u32)__shfl_xor((int)s0a, 32), e0b = (u32)__shfl_xor((int)s0b, 32);
    u32 m0a = hl ? g1a : g0a, m0b = hl ? g1b : g0b;
    u32 s1a = hl ? g2a : g3a, s1b = hl ? g2b : g3b;
    u32 e1a = (u32)__shfl_xor((int)s1a, 32), e1b = (u32)__shfl_xor((int)s1b, 32);
    u32 m1a = hl ? g3a : g2a, m1b = hl ? g3b : g2b;
    u32x4 A0 = { hl ? e0a : m0a, hl ? e0b : m0b, hl ? m0a : e0a, hl ? m0b : e0b };
    u32x4 A1 = { hl ? e1a : m1a, hl ? e1b : m1b, hl ? m1a : e1a, hl ? m1b : e1b };
    bf16x8 pa0 = __builtin_bit_cast(bf16x8, A0);
    bf16x8 pa1 = __builtin_bit_cast(bf16x8, A1);
    acc0 = __builtin_amdgcn_mfma_f32_32x32x16_bf16(vf00, pa0, acc0, 0, 0, 0);
    acc0 = __builtin_amdgcn_mfma_f32_32x32x16_bf16(vf10, pa1, acc0, 0, 0, 0);
    acc1 = __builtin_amdgcn_mfma_f32_32x32x16_bf16(vf01, pa0, acc1, 0, 0, 0);
    acc1 = __builtin_amdgcn_mfma_f32_32x32x16_bf16(vf11, pa1, acc1, 0, 0, 0);
  }
  // epilogue: normalize, transpose via swizzled LDS, coalesced 16B stores
  float inv = __builtin_amdgcn_rcpf(l);
  char* tbc = (char*)tb;
  #pragma unroll
  for (int r = 0; r < 16; ++r){
    int d0 = (r & 3) + 8*(r >> 2) + 4*hl;
    *(u16*)(tbc + lq*128 + ((2*d0)      ^ ((lq & 7) << 4))) = f2bf(acc0[r] * inv);
    *(u16*)(tbc + lq*128 + ((2*(d0+32)) ^ ((lq & 7) << 4))) = f2bf(acc1[r] * inv);
  }
  int qr2 = lane >> 1, chb = (lane & 1) * 4;
  u16* cp = ctx + (size_t)(b*SEQ + q0 + qr2)*D_MODEL + h*HEAD_DIM;
  #pragma unroll
  for (int i = 0; i < 4; ++i){
    int ch = chb + i;
    u16x8 vv = *(const u16x8*)(tbc + qr2*128 + 16*(ch ^ (qr2 & 7)));
    *(u16x8*)&cp[ch*8] = vv;
  }
}

extern "C" void kernel_launch(void* const* d_in, const int* in_sizes, int n_in,
                              void* d_out, int out_size, void* d_ws, size_t ws_size,
                              hipStream_t stream){
  const float* x  = (const float*)d_in[0];
  const int*  pos = (const int*)d_in[1];
  const float* Wq = (const float*)d_in[2];
  const float* Wk = (const float*)d_in[3];
  const float* Wv = (const float*)d_in[4];
  const float* Wo = (const float*)d_in[5];
  float* out = (float*)d_out;
  char* ws = (char*)d_ws;
  u16* xb   = (u16*)(ws);                    // 16 MB  x bf16 (reused as ctx later)
  u16* wt   = (u16*)(ws + 16777216);         // 8 MB   Wt q,k,v,o transposed bf16
  u16* qb   = (u16*)(ws + 25165824);         // 16 MB  q row-major (roped, scaled)
  u16* kbh  = (u16*)(ws + 41943040);         // 16 MB  k [b][h][s][64] (roped)
  u16* vt2  = (u16*)(ws + 58720256);         // 16 MB  v [b][h][s/16][d][16]
  float2* tab = (float2*)(ws + 75497472);    // 512 KB rope table
  u16* ctxb = xb;

  k_cvt_x<<<(MROWS*D_MODEL/4)/256, 256, 0, stream>>>(x, xb, MROWS*D_MODEL/4);
  k_transpose_w<<<dim3(32,32,4), dim3(32,8), 0, stream>>>(Wq, Wk, Wv, Wo, wt);
  k_rope_tab<<<(SEQ*32)/256, 256, 0, stream>>>(pos, tab);
  k_gemm_qkv<<<dim3(64,24), 256, 0, stream>>>(xb, wt, tab, qb, kbh, vt2);
  k_attn<<<dim3(1024), 256, 0, stream>>>(qb, kbh, vt2, ctxb);
  k_gemm_wo<<<dim3(64,8), 256, 0, stream>>>(ctxb, wt + 3145728, out);
}

// Round 4
// 225.048 us; speedup vs baseline: 2.6225x; 1.1359x over previous
//
#include <hip/hip_runtime.h>

typedef unsigned short u16;
typedef unsigned int   u32;
typedef __bf16  bf16x8 __attribute__((ext_vector_type(8)));
typedef float   f32x4  __attribute__((ext_vector_type(4)));
typedef float   f32x16 __attribute__((ext_vector_type(16)));
typedef u16     u16x4  __attribute__((ext_vector_type(4)));
typedef u16     u16x8  __attribute__((ext_vector_type(8)));
typedef u32     u32x4  __attribute__((ext_vector_type(4)));

#define D_MODEL 1024
#define N_HEADS 16
#define HEAD_DIM 64
#define BATCH 4
#define SEQ 2048
#define MROWS (BATCH*SEQ)

__device__ __forceinline__ u16 f2bf(float f){
  unsigned u = __builtin_bit_cast(unsigned, f);
  u += 0x7fffu + ((u >> 16) & 1u);
  return (u16)(u >> 16);
}
__device__ __forceinline__ float bf2f(u16 h){
  unsigned u = ((unsigned)h) << 16;
  return __builtin_bit_cast(float, u);
}
__device__ __forceinline__ u32 cvtpk(float a, float b){
  u32 r; asm("v_cvt_pk_bf16_f32 %0, %1, %2" : "=v"(r) : "v"(a), "v"(b)); return r;
}
__device__ __forceinline__ void gload_lds16(const u16* g, u16* l){
  __builtin_amdgcn_global_load_lds((const __attribute__((address_space(1))) void*)g,
                                   (__attribute__((address_space(3))) void*)l, 16, 0, 0);
}

// ---------- x fp32 -> bf16 ----------
__global__ void k_cvt_x(const float* __restrict__ x, u16* __restrict__ xb, int n4){
  int i = blockIdx.x * 256 + threadIdx.x;
  if (i >= n4) return;
  float4 v = reinterpret_cast<const float4*>(x)[i];
  u16x4 o;
  o.x = f2bf(v.x); o.y = f2bf(v.y); o.z = f2bf(v.z); o.w = f2bf(v.w);
  *reinterpret_cast<u16x4*>(xb + (size_t)i * 4) = o;
}

// ---------- W fp32 [k][n] -> bf16 Wt [n][k] ----------
__global__ void k_transpose_w(const float* __restrict__ Wq, const float* __restrict__ Wk,
                              const float* __restrict__ Wv, const float* __restrict__ Wo,
                              u16* __restrict__ wt){
  __shared__ float t[32][33];
  int z = blockIdx.z;
  const float* W = (z==0)?Wq:(z==1)?Wk:(z==2)?Wv:Wo;
  u16* O = wt + (size_t)z * (D_MODEL*(size_t)D_MODEL);
  int n0 = blockIdx.x*32, k0 = blockIdx.y*32;
  int tx = threadIdx.x, ty = threadIdx.y;
  #pragma unroll
  for (int i = ty; i < 32; i += 8) t[i][tx] = W[(size_t)(k0+i)*D_MODEL + n0 + tx];
  __syncthreads();
  #pragma unroll
  for (int i = ty; i < 32; i += 8) O[(size_t)(n0+i)*D_MODEL + k0 + tx] = f2bf(t[tx][i]);
}

// ---------- RoPE cos/sin table ----------
__global__ void k_rope_tab(const int* __restrict__ pos, float2* __restrict__ tab){
  int i = blockIdx.x * 256 + threadIdx.x;          // SEQ*32 threads
  int s = i >> 5, f = i & 31;
  float inv = exp2f(-(float)f * (13.287712379549449f / 32.0f)); // theta^(-f/32)
  float a = (float)pos[s] * inv;
  float sn, cs;
  sincosf(a, &sn, &cs);
  tab[i] = make_float2(cs, sn);
}

// ---------- fused QKV GEMM: [8192][1024] @ wt[3072][1024]^T, RoPE in epilogue ----------
__global__ __launch_bounds__(256) void k_gemm_qkv(const u16* __restrict__ A, const u16* __restrict__ Bt,
                                                  const float2* __restrict__ tab,
                                                  u16* __restrict__ qout, u16* __restrict__ kout,
                                                  u16* __restrict__ vout){
  __shared__ u16 sA[128*32];
  __shared__ u16 sB[128*32];
  const int K = 1024;
  int tid = threadIdx.x, lane = tid & 63, w = tid >> 6;
  int lr = lane & 15, lg = lane >> 4;
  int m0 = blockIdx.x * 128, n0 = blockIdx.y * 128;
  int wr = w >> 1, wc = w & 1;
  int srow = lane >> 2;
  int schunk = (lane & 3) ^ (srow & 3);
  const u16* ga0 = A  + (size_t)(m0 + w*32 + srow)*K + schunk*8;
  const u16* gb0 = Bt + (size_t)(n0 + w*32 + srow)*K + schunk*8;
  u16* la = sA + (size_t)w*32*32;
  u16* lb = sB + (size_t)w*32*32;
  f32x4 acc[4][4] = {};
  for (int k0 = 0; k0 < K; k0 += 32){
    gload_lds16(ga0 + k0,        la);
    gload_lds16(ga0 + 16*K + k0, la + 16*32);
    gload_lds16(gb0 + k0,        lb);
    gload_lds16(gb0 + 16*K + k0, lb + 16*32);
    __syncthreads();
    bf16x8 af[4], bfr[4];
    #pragma unroll
    for (int mi = 0; mi < 4; mi++){
      int row = wr*64 + mi*16 + lr;
      af[mi] = *(const bf16x8*)&sA[row*32 + ((lg ^ (row & 3)) * 8)];
    }
    #pragma unroll
    for (int ni = 0; ni < 4; ni++){
      int row = wc*64 + ni*16 + lr;
      bfr[ni] = *(const bf16x8*)&sB[row*32 + ((lg ^ (row & 3)) * 8)];
    }
    #pragma unroll
    for (int mi = 0; mi < 4; mi++)
      #pragma unroll
      for (int ni = 0; ni < 4; ni++)
        acc[mi][ni] = __builtin_amdgcn_mfma_f32_16x16x32_bf16(af[mi], bfr[ni], acc[mi][ni], 0, 0, 0);
    __syncthreads();
  }
  const int which = n0 >> 10;                 // 0=q 1=k 2=v
  #pragma unroll
  for (int mi = 0; mi < 4; mi++){
    int row = m0 + wr*64 + mi*16 + lg*4;
    #pragma unroll
    for (int ni = 0; ni < 4; ni++){
      int col = n0 + wc*64 + ni*16 + lr;
      int cm = col & 1023;
      int hh = cm >> 6, d = cm & 63;
      f32x4 vv = acc[mi][ni];
      #pragma unroll
      for (int r = 0; r < 4; r++){
        int rr = row + r;
        int bb = rr >> 11, s = rr & (SEQ-1);
        float val = vv[r];
        if (which < 2){
          float partner = __shfl_xor(val, 1);
          float2 cs = tab[s*32 + (d >> 1)];
          float o = (d & 1) ? (partner*cs.y + val*cs.x) : (val*cs.x - partner*cs.y);
          if (which == 0){
            o *= 0.18033688011112042f;        // 0.125 * log2(e)
            qout[(size_t)rr*1024 + cm] = f2bf(o);
          } else {
            kout[(((size_t)(bb*N_HEADS + hh))*SEQ + s)*64 + d] = f2bf(o);
          }
        } else {
          vout[(((size_t)(bb*N_HEADS + hh))*(SEQ/16) + (s >> 4))*1024 + d*16 + (s & 15)] = f2bf(val);
        }
      }
    }
  }
}

// ---------- Wo GEMM: out f32 = ctx(bf16)[8192][1024] @ wt_o[1024][1024]^T ----------
__global__ __launch_bounds__(256) void k_gemm_wo(const u16* __restrict__ A, const u16* __restrict__ Bt,
                                                 float* __restrict__ Cv){
  __shared__ u16 sA[128*32];
  __shared__ u16 sB[128*32];
  const int K = 1024, N = 1024;
  int tid = threadIdx.x, lane = tid & 63, w = tid >> 6;
  int lr = lane & 15, lg = lane >> 4;
  int m0 = blockIdx.x * 128, n0 = blockIdx.y * 128;
  int wr = w >> 1, wc = w & 1;
  int srow = lane >> 2;
  int schunk = (lane & 3) ^ (srow & 3);
  const u16* ga0 = A  + (size_t)(m0 + w*32 + srow)*K + schunk*8;
  const u16* gb0 = Bt + (size_t)(n0 + w*32 + srow)*K + schunk*8;
  u16* la = sA + (size_t)w*32*32;
  u16* lb = sB + (size_t)w*32*32;
  f32x4 acc[4][4] = {};
  for (int k0 = 0; k0 < K; k0 += 32){
    gload_lds16(ga0 + k0,        la);
    gload_lds16(ga0 + 16*K + k0, la + 16*32);
    gload_lds16(gb0 + k0,        lb);
    gload_lds16(gb0 + 16*K + k0, lb + 16*32);
    __syncthreads();
    bf16x8 af[4], bfr[4];
    #pragma unroll
    for (int mi = 0; mi < 4; mi++){
      int row = wr*64 + mi*16 + lr;
      af[mi] = *(const bf16x8*)&sA[row*32 + ((lg ^ (row & 3)) * 8)];
    }
    #pragma unroll
    for (int ni = 0; ni < 4; ni++){
      int row = wc*64 + ni*16 + lr;
      bfr[ni] = *(const bf16x8*)&sB[row*32 + ((lg ^ (row & 3)) * 8)];
    }
    #pragma unroll
    for (int mi = 0; mi < 4; mi++)
      #pragma unroll
      for (int ni = 0; ni < 4; ni++)
        acc[mi][ni] = __builtin_amdgcn_mfma_f32_16x16x32_bf16(af[mi], bfr[ni], acc[mi][ni], 0, 0, 0);
    __syncthreads();
  }
  #pragma unroll
  for (int mi = 0; mi < 4; mi++){
    int row = m0 + wr*64 + mi*16 + lg*4;
    #pragma unroll
    for (int ni = 0; ni < 4; ni++){
      int col = n0 + wc*64 + ni*16 + lr;
      f32x4 v = acc[mi][ni];
      #pragma unroll
      for (int r = 0; r < 4; r++)
        Cv[(size_t)(row + r)*N + col] = v[r];
    }
  }
}

// ---------- causal flash attention: swapped-operand 32x32, coalesced K/V layouts ----------
// grid 1024 blocks x 256 thr (4 waves). Block B: bh = B&63, g = B>>6 (0..15).
// Tile set {g, 63-g, 31-g, 32+g} rotated by (w + B>>8)&3.
// __launch_bounds__(256,4): 128-VGPR budget -> hold the ~110 live regs without spill.
__global__ __launch_bounds__(256, 4) void k_attn(const u16* __restrict__ q, const u16* __restrict__ k2,
                                                 const u16* __restrict__ v2, u16* __restrict__ ctx){
  __shared__ u16 tp[4][2048];                 // per-wave 4KB transpose buffer
  const int lane = threadIdx.x & 63, w = threadIdx.x >> 6;
  const int lq = lane & 31, hl = lane >> 5;
  const int B = blockIdx.x;
  const int bh = B & 63, g = B >> 6;
  const int b = bh >> 4, h = bh & 15;
  const int sel = (w + (B >> 8)) & 3;
  int qi = (sel == 0) ? g : (sel == 1) ? (63 - g) : (sel == 2) ? (31 - g) : (32 + g);
  const int q0 = qi * 32;
  const u16* kbase = k2 + (size_t)bh*SEQ*64;
  const u16* vbase = v2 + (size_t)bh*(SEQ/16)*1024;
  u16* tb = tp[w];

  const u16* qr_ = &q[(size_t)(b*SEQ + q0 + lq)*D_MODEL + h*HEAD_DIM + hl*8];
  bf16x8 qf0 = *(const bf16x8*)&qr_[0];
  bf16x8 qf1 = *(const bf16x8*)&qr_[16];
  bf16x8 qf2 = *(const bf16x8*)&qr_[32];
  bf16x8 qf3 = *(const bf16x8*)&qr_[48];
  f32x16 acc0 = {}, acc1 = {};
  float m = -3.0e38f, l = 0.f;               // l: per-lane partial, merged in epilogue

  for (int j0 = 0; j0 <= q0; j0 += 32){
    const u16* kr = &kbase[(size_t)(j0 + lq)*64 + hl*8];
    bf16x8 kf0 = *(const bf16x8*)&kr[0];
    bf16x8 kf1 = *(const bf16x8*)&kr[16];
    bf16x8 kf2 = *(const bf16x8*)&kr[32];
    bf16x8 kf3 = *(const bf16x8*)&kr[48];
    const u16* vr = &vbase[(size_t)(j0 >> 4)*1024 + lq*16 + hl*8];
    bf16x8 vf00 = *(const bf16x8*)&vr[0];
    bf16x8 vf10 = *(const bf16x8*)&vr[1024];
    bf16x8 vf01 = *(const bf16x8*)&vr[512];
    bf16x8 vf11 = *(const bf16x8*)&vr[1536];

    f32x16 S = {};
    S = __builtin_amdgcn_mfma_f32_32x32x16_bf16(kf0, qf0, S, 0, 0, 0);
    S = __builtin_amdgcn_mfma_f32_32x32x16_bf16(kf1, qf1, S, 0, 0, 0);
    S = __builtin_amdgcn_mfma_f32_32x32x16_bf16(kf2, qf2, S, 0, 0, 0);
    S = __builtin_amdgcn_mfma_f32_32x32x16_bf16(kf3, qf3, S, 0, 0, 0);

    if (j0 == q0){                            // diagonal tile: mask k > q
      #pragma unroll
      for (int r = 0; r < 16; ++r){
        int kk = (r & 3) + 8*(r >> 2) + 4*hl;
        if (kk > lq) S[r] = -3.0e38f;
      }
    }
    float a0 = fmaxf(fmaxf(S[0],S[1]),  fmaxf(S[2],S[3]));
    float a1 = fmaxf(fmaxf(S[4],S[5]),  fmaxf(S[6],S[7]));
    float a2 = fmaxf(fmaxf(S[8],S[9]),  fmaxf(S[10],S[11]));
    float a3 = fmaxf(fmaxf(S[12],S[13]),fmaxf(S[14],S[15]));
    float pm = fmaxf(fmaxf(a0,a1), fmaxf(a2,a3));
    pm = fmaxf(pm, __shfl_xor(pm, 32));
    if (__any(pm > m + 8.f)){                 // defer-max (T13)
      float mn = fmaxf(m, pm);
      float cr = __builtin_amdgcn_exp2f(m - mn);
      l *= cr;
      #pragma unroll
      for (int r = 0; r < 16; ++r){ acc0[r] *= cr; acc1[r] *= cr; }
      m = mn;
    }
    #pragma unroll
    for (int r = 0; r < 16; ++r) S[r] = __builtin_amdgcn_exp2f(S[r] - m);   // P in place of S
    float s0_ = (S[0]+S[1]) + (S[2]+S[3]);
    float s1_ = (S[4]+S[5]) + (S[6]+S[7]);
    float s2_ = (S[8]+S[9]) + (S[10]+S[11]);
    float s3_ = (S[12]+S[13]) + (S[14]+S[15]);
    l += (s0_+s1_) + (s2_+s3_);               // per-lane partial (no shuffle)
    // pack P -> bf16 pairs (cvt_pk); group g holds k=4g..4g+3 (pre-exchange, local hi=hl)
    u32 g0a = cvtpk(S[0], S[1]),  g0b = cvtpk(S[2], S[3]);
    u32 g1a = cvtpk(S[4], S[5]),  g1b = cvtpk(S[6], S[7]);
    u32 g2a = cvtpk(S[8], S[9]),  g2b = cvtpk(S[10],S[11]);
    u32 g3a = cvtpk(S[12],S[13]), g3b = cvtpk(S[14],S[15]);
    u32 s0a = hl ? g0a : g1a, s0b = hl ? g0b : g1b;
    u32 e0a = (u32)__shfl_xor((int)s0a, 32), e0b = (u32)__shfl_xor((int)s0b, 32);
    u32 m0a = hl ? g1a : g0a, m0b = hl ? g1b : g0b;
    u32 s1a = hl ? g2a : g3a, s1b = hl ? g2b : g3b;
    u32 e1a = (u32)__shfl_xor((int)s1a, 32), e1b = (u32)__shfl_xor((int)s1b, 32);
    u32 m1a = hl ? g3a : g2a, m1b = hl ? g3b : g2b;
    u32x4 A0 = { hl ? e0a : m0a, hl ? e0b : m0b, hl ? m0a : e0a, hl ? m0b : e0b };
    u32x4 A1 = { hl ? e1a : m1a, hl ? e1b : m1b, hl ? m1a : e1a, hl ? m1b : e1b };
    bf16x8 pa0 = __builtin_bit_cast(bf16x8, A0);
    bf16x8 pa1 = __builtin_bit_cast(bf16x8, A1);
    acc0 = __builtin_amdgcn_mfma_f32_32x32x16_bf16(vf00, pa0, acc0, 0, 0, 0);
    acc0 = __builtin_amdgcn_mfma_f32_32x32x16_bf16(vf10, pa1, acc0, 0, 0, 0);
    acc1 = __builtin_amdgcn_mfma_f32_32x32x16_bf16(vf01, pa0, acc1, 0, 0, 0);
    acc1 = __builtin_amdgcn_mfma_f32_32x32x16_bf16(vf11, pa1, acc1, 0, 0, 0);
  }
  // epilogue: merge the lane-pair partial denominators, normalize, transpose, store
  l += __shfl_xor(l, 32);
  float inv = __builtin_amdgcn_rcpf(l);
  char* tbc = (char*)tb;
  #pragma unroll
  for (int r = 0; r < 16; ++r){
    int d0 = (r & 3) + 8*(r >> 2) + 4*hl;
    *(u16*)(tbc + lq*128 + ((2*d0)      ^ ((lq & 7) << 4))) = f2bf(acc0[r] * inv);
    *(u16*)(tbc + lq*128 + ((2*(d0+32)) ^ ((lq & 7) << 4))) = f2bf(acc1[r] * inv);
  }
  int qr2 = lane >> 1, chb = (lane & 1) * 4;
  u16* cp = ctx + (size_t)(b*SEQ + q0 + qr2)*D_MODEL + h*HEAD_DIM;
  #pragma unroll
  for (int i = 0; i < 4; ++i){
    int ch = chb + i;
    u16x8 vv = *(const u16x8*)(tbc + qr2*128 + 16*(ch ^ (qr2 & 7)));
    *(u16x8*)&cp[ch*8] = vv;
  }
}

extern "C" void kernel_launch(void* const* d_in, const int* in_sizes, int n_in,
                              void* d_out, int out_size, void* d_ws, size_t ws_size,
                              hipStream_t stream){
  const float* x  = (const float*)d_in[0];
  const int*  pos = (const int*)d_in[1];
  const float* Wq = (const float*)d_in[2];
  const float* Wk = (const float*)d_in[3];
  const float* Wv = (const float*)d_in[4];
  const float* Wo = (const float*)d_in[5];
  float* out = (float*)d_out;
  char* ws = (char*)d_ws;
  u16* xb   = (u16*)(ws);                    // 16 MB  x bf16 (reused as ctx later)
  u16* wt   = (u16*)(ws + 16777216);         // 8 MB   Wt q,k,v,o transposed bf16
  u16* qb   = (u16*)(ws + 25165824);         // 16 MB  q row-major (roped, scaled)
  u16* kbh  = (u16*)(ws + 41943040);         // 16 MB  k [b][h][s][64] (roped)
  u16* vt2  = (u16*)(ws + 58720256);         // 16 MB  v [b][h][s/16][d][16]
  float2* tab = (float2*)(ws + 75497472);    // 512 KB rope table
  u16* ctxb = xb;

  k_cvt_x<<<(MROWS*D_MODEL/4)/256, 256, 0, stream>>>(x, xb, MROWS*D_MODEL/4);
  k_transpose_w<<<dim3(32,32,4), dim3(32,8), 0, stream>>>(Wq, Wk, Wv, Wo, wt);
  k_rope_tab<<<(SEQ*32)/256, 256, 0, stream>>>(pos, tab);
  k_gemm_qkv<<<dim3(64,24), 256, 0, stream>>>(xb, wt, tab, qb, kbh, vt2);
  k_attn<<<dim3(1024), 256, 0, stream>>>(qb, kbh, vt2, ctxb);
  k_gemm_wo<<<dim3(64,8), 256, 0, stream>>>(ctxb, wt + 3145728, out);
}

// Round 5
// 210.225 us; speedup vs baseline: 2.8074x; 1.0705x over previous
//
#include <hip/hip_runtime.h>

typedef unsigned short u16;
typedef unsigned int   u32;
typedef __bf16  bf16x8 __attribute__((ext_vector_type(8)));
typedef float   f32x4  __attribute__((ext_vector_type(4)));
typedef float   f32x16 __attribute__((ext_vector_type(16)));
typedef u16     u16x4  __attribute__((ext_vector_type(4)));
typedef u16     u16x8  __attribute__((ext_vector_type(8)));
typedef u32     u32x4  __attribute__((ext_vector_type(4)));

#define D_MODEL 1024
#define N_HEADS 16
#define HEAD_DIM 64
#define BATCH 4
#define SEQ 2048
#define MROWS (BATCH*SEQ)

__device__ __forceinline__ u16 f2bf(float f){
  unsigned u = __builtin_bit_cast(unsigned, f);
  u += 0x7fffu + ((u >> 16) & 1u);
  return (u16)(u >> 16);
}
__device__ __forceinline__ float bf2f(u16 h){
  unsigned u = ((unsigned)h) << 16;
  return __builtin_bit_cast(float, u);
}
__device__ __forceinline__ u32 cvtpk(float a, float b){
  u32 r; asm("v_cvt_pk_bf16_f32 %0, %1, %2" : "=v"(r) : "v"(a), "v"(b)); return r;
}
__device__ __forceinline__ void gload_lds16(const u16* g, u16* l){
  __builtin_amdgcn_global_load_lds((const __attribute__((address_space(1))) void*)g,
                                   (__attribute__((address_space(3))) void*)l, 16, 0, 0);
}

// ---------- x fp32 -> bf16 ----------
__global__ void k_cvt_x(const float* __restrict__ x, u16* __restrict__ xb, int n4){
  int i = blockIdx.x * 256 + threadIdx.x;
  if (i >= n4) return;
  float4 v = reinterpret_cast<const float4*>(x)[i];
  u16x4 o;
  o.x = f2bf(v.x); o.y = f2bf(v.y); o.z = f2bf(v.z); o.w = f2bf(v.w);
  *reinterpret_cast<u16x4*>(xb + (size_t)i * 4) = o;
}

// ---------- W fp32 [k][n] -> bf16 Wt [n][k] ----------
__global__ void k_transpose_w(const float* __restrict__ Wq, const float* __restrict__ Wk,
                              const float* __restrict__ Wv, const float* __restrict__ Wo,
                              u16* __restrict__ wt){
  __shared__ float t[32][33];
  int z = blockIdx.z;
  const float* W = (z==0)?Wq:(z==1)?Wk:(z==2)?Wv:Wo;
  u16* O = wt + (size_t)z * (D_MODEL*(size_t)D_MODEL);
  int n0 = blockIdx.x*32, k0 = blockIdx.y*32;
  int tx = threadIdx.x, ty = threadIdx.y;
  #pragma unroll
  for (int i = ty; i < 32; i += 8) t[i][tx] = W[(size_t)(k0+i)*D_MODEL + n0 + tx];
  __syncthreads();
  #pragma unroll
  for (int i = ty; i < 32; i += 8) O[(size_t)(n0+i)*D_MODEL + k0 + tx] = f2bf(t[tx][i]);
}

// ---------- RoPE cos/sin table ----------
__global__ void k_rope_tab(const int* __restrict__ pos, float2* __restrict__ tab){
  int i = blockIdx.x * 256 + threadIdx.x;          // SEQ*32 threads
  int s = i >> 5, f = i & 31;
  float inv = exp2f(-(float)f * (13.287712379549449f / 32.0f)); // theta^(-f/32)
  float a = (float)pos[s] * inv;
  float sn, cs;
  sincosf(a, &sn, &cs);
  tab[i] = make_float2(cs, sn);
}

// ---------- 2-phase double-buffered GEMM, 128x128 tile, BK=32, 4 waves ----------
// MODE 0: fused QKV (RoPE fold, q/k/v routed outputs). MODE 1: f32 out (Wo).
template<int MODE>
__global__ __launch_bounds__(256, 4) void k_gemm2(const u16* __restrict__ A, const u16* __restrict__ Bt,
                                                  const float2* __restrict__ tab,
                                                  u16* __restrict__ qout, u16* __restrict__ kout,
                                                  u16* __restrict__ vout, float* __restrict__ fout){
  __shared__ u16 sA0[128*32], sA1[128*32], sB0[128*32], sB1[128*32];   // 32 KB dbuf
  const int K = 1024;
  int tid = threadIdx.x, lane = tid & 63, w = tid >> 6;
  int lr = lane & 15, lg = lane >> 4;
  int m0 = blockIdx.x * 128, n0 = blockIdx.y * 128;
  int wm = w >> 1, wn = w & 1;
  int srow = lane >> 2, scol = (lane & 3) * 8;
  const u16* ga = A  + (size_t)(m0 + w*16 + srow)*K + scol;   // + i*64*K + t*32
  const u16* gb = Bt + (size_t)(n0 + w*16 + srow)*K + scol;
  f32x4 acc[4][4] = {};

#define STAGE2(t, sa, sb) \
    gload_lds16(ga + (size_t)(t)*32,         sa + (w*16)*32); \
    gload_lds16(ga + (size_t)(t)*32 + 64*K,  sa + (64 + w*16)*32); \
    gload_lds16(gb + (size_t)(t)*32,         sb + (w*16)*32); \
    gload_lds16(gb + (size_t)(t)*32 + 64*K,  sb + (64 + w*16)*32);

#define COMP2(sa, sb) { \
    bf16x8 af[4], bv[4]; \
    _Pragma("unroll") \
    for (int mi = 0; mi < 4; mi++) \
      af[mi] = *(const bf16x8*)&sa[(wm*64 + mi*16 + lr)*32 + lg*8]; \
    _Pragma("unroll") \
    for (int ni = 0; ni < 4; ni++) \
      bv[ni] = *(const bf16x8*)&sb[(wn*64 + ni*16 + lr)*32 + lg*8]; \
    _Pragma("unroll") \
    for (int mi = 0; mi < 4; mi++){ \
      _Pragma("unroll") \
      for (int ni = 0; ni < 4; ni++) \
        acc[mi][ni] = __builtin_amdgcn_mfma_f32_16x16x32_bf16(af[mi], bv[ni], acc[mi][ni], 0, 0, 0); \
    } }

  STAGE2(0, sA0, sB0);
  __syncthreads();
  for (int t2 = 0; t2 < 16; ++t2){
    int t = t2 * 2;
    STAGE2(t+1, sA1, sB1);       // issue next-tile loads BEFORE computing current
    COMP2(sA0, sB0);
    __syncthreads();             // drains this wave's vmcnt; all stages landed
    if (t + 2 < 32){ STAGE2(t+2, sA0, sB0); }
    COMP2(sA1, sB1);
    __syncthreads();
  }
#undef STAGE2
#undef COMP2

  #pragma unroll
  for (int mi = 0; mi < 4; mi++){
    int row = m0 + wm*64 + mi*16 + lg*4;
    #pragma unroll
    for (int ni = 0; ni < 4; ni++){
      int col = n0 + wn*64 + ni*16 + lr;
      f32x4 vv = acc[mi][ni];
      if (MODE == 1){
        #pragma unroll
        for (int r = 0; r < 4; r++)
          fout[(size_t)(row + r)*1024 + col] = vv[r];
      } else {
        int cm = col & 1023;
        int hh = cm >> 6, d = cm & 63;
        const int which = n0 >> 10;             // 0=q 1=k 2=v
        #pragma unroll
        for (int r = 0; r < 4; r++){
          int rr = row + r;
          int bb = rr >> 11, s = rr & (SEQ-1);
          float val = vv[r];
          if (which < 2){
            float partner = __shfl_xor(val, 1);
            float2 cs = tab[s*32 + (d >> 1)];
            float o = (d & 1) ? (partner*cs.y + val*cs.x) : (val*cs.x - partner*cs.y);
            if (which == 0){
              o *= 0.18033688011112042f;        // 0.125 * log2(e)
              qout[(size_t)rr*1024 + cm] = f2bf(o);
            } else {
              kout[(((size_t)(bb*N_HEADS + hh))*SEQ + s)*64 + d] = f2bf(o);
            }
          } else {
            vout[(((size_t)(bb*N_HEADS + hh))*(SEQ/16) + (s >> 4))*1024 + d*16 + (s & 15)] = f2bf(val);
          }
        }
      }
    }
  }
}

// ---------- causal flash attention: 1-wave blocks, K-prefetch software pipeline ----------
// grid 4096 x 64 thr. Block B: bh = B&63, qi = 63 - (B>>6) (longest tiles launch first).
// QK^T: mfma(K,Q) -> S[k][q], col=lane&31=q. PV: mfma(Vt,P) -> acc[d][q].
__global__ __launch_bounds__(64, 3) void k_attn(const u16* __restrict__ q, const u16* __restrict__ k2,
                                                const u16* __restrict__ v2, u16* __restrict__ ctx){
  __shared__ u16 tp[2048];
  const int lane = threadIdx.x;
  const int lq = lane & 31, hl = lane >> 5;
  const int B = blockIdx.x;
  const int bh = B & 63;
  const int qi = 63 - (B >> 6);
  const int b = bh >> 4, h = bh & 15;
  const int q0 = qi * 32;
  const u16* kl = k2 + (size_t)bh*SEQ*64 + (size_t)lq*64 + hl*8;
  const u16* vl = v2 + (size_t)bh*(SEQ/16)*1024 + lq*16 + hl*8;
  const u16* qr_ = q + (size_t)(b*SEQ + q0 + lq)*D_MODEL + h*HEAD_DIM + hl*8;
  bf16x8 qf0 = *(const bf16x8*)&qr_[0];
  bf16x8 qf1 = *(const bf16x8*)&qr_[16];
  bf16x8 qf2 = *(const bf16x8*)&qr_[32];
  bf16x8 qf3 = *(const bf16x8*)&qr_[48];
  f32x16 acc0 = {}, acc1 = {};
  float m = -3.0e38f, l = 0.f;
  // preload K tile 0
  bf16x8 kc0 = *(const bf16x8*)&kl[0];
  bf16x8 kc1 = *(const bf16x8*)&kl[16];
  bf16x8 kc2 = *(const bf16x8*)&kl[32];
  bf16x8 kc3 = *(const bf16x8*)&kl[48];

  #pragma unroll 2
  for (int j0 = 0; j0 <= q0; j0 += 32){
    int jn = (j0 + 32 <= q0) ? (j0 + 32) : q0;      // clamped prefetch target
    const u16* kn = kl + (size_t)jn*64;
    bf16x8 kn0 = *(const bf16x8*)&kn[0];
    bf16x8 kn1 = *(const bf16x8*)&kn[16];
    bf16x8 kn2 = *(const bf16x8*)&kn[32];
    bf16x8 kn3 = *(const bf16x8*)&kn[48];
    const u16* vr = vl + (size_t)(j0 >> 4)*1024;    // V issued early; used after softmax
    bf16x8 vf00 = *(const bf16x8*)&vr[0];
    bf16x8 vf10 = *(const bf16x8*)&vr[1024];
    bf16x8 vf01 = *(const bf16x8*)&vr[512];
    bf16x8 vf11 = *(const bf16x8*)&vr[1536];

    f32x16 S = {};
    S = __builtin_amdgcn_mfma_f32_32x32x16_bf16(kc0, qf0, S, 0, 0, 0);
    S = __builtin_amdgcn_mfma_f32_32x32x16_bf16(kc1, qf1, S, 0, 0, 0);
    S = __builtin_amdgcn_mfma_f32_32x32x16_bf16(kc2, qf2, S, 0, 0, 0);
    S = __builtin_amdgcn_mfma_f32_32x32x16_bf16(kc3, qf3, S, 0, 0, 0);

    if (j0 == q0){                            // diagonal tile: mask k > q
      #pragma unroll
      for (int r = 0; r < 16; ++r){
        int kk = (r & 3) + 8*(r >> 2) + 4*hl;
        if (kk > lq) S[r] = -3.0e38f;
      }
    }
    float a0 = fmaxf(fmaxf(S[0],S[1]),  fmaxf(S[2],S[3]));
    float a1 = fmaxf(fmaxf(S[4],S[5]),  fmaxf(S[6],S[7]));
    float a2 = fmaxf(fmaxf(S[8],S[9]),  fmaxf(S[10],S[11]));
    float a3 = fmaxf(fmaxf(S[12],S[13]),fmaxf(S[14],S[15]));
    float pm = fmaxf(fmaxf(a0,a1), fmaxf(a2,a3));
    pm = fmaxf(pm, __shfl_xor(pm, 32));
    if (__any(pm > m + 8.f)){                 // defer-max (T13)
      float mn = fmaxf(m, pm);
      float cr = __builtin_amdgcn_exp2f(m - mn);
      l *= cr;
      #pragma unroll
      for (int r = 0; r < 16; ++r){ acc0[r] *= cr; acc1[r] *= cr; }
      m = mn;
    }
    #pragma unroll
    for (int r = 0; r < 16; ++r) S[r] = __builtin_amdgcn_exp2f(S[r] - m);   // P in place
    float s0_ = (S[0]+S[1]) + (S[2]+S[3]);
    float s1_ = (S[4]+S[5]) + (S[6]+S[7]);
    float s2_ = (S[8]+S[9]) + (S[10]+S[11]);
    float s3_ = (S[12]+S[13]) + (S[14]+S[15]);
    l += (s0_+s1_) + (s2_+s3_);               // per-lane partial (merged in epilogue)
    // pack P -> bf16 pairs (cvt_pk); exchange with lane^32 to build A-fragments
    u32 g0a = cvtpk(S[0], S[1]),  g0b = cvtpk(S[2], S[3]);
    u32 g1a = cvtpk(S[4], S[5]),  g1b = cvtpk(S[6], S[7]);
    u32 g2a = cvtpk(S[8], S[9]),  g2b = cvtpk(S[10],S[11]);
    u32 g3a = cvtpk(S[12],S[13]), g3b = cvtpk(S[14],S[15]);
    u32 s0a = hl ? g0a : g1a, s0b = hl ? g0b : g1b;
    u32 e0a = (u32)__shfl_xor((int)s0a, 32), e0b = (u32)__shfl_xor((int)s0b, 32);
    u32 m0a = hl ? g1a : g0a, m0b = hl ? g1b : g0b;
    u32 s1a = hl ? g2a : g3a, s1b = hl ? g2b : g3b;
    u32 e1a = (u32)__shfl_xor((int)s1a, 32), e1b = (u32)__shfl_xor((int)s1b, 32);
    u32 m1a = hl ? g3a : g2a, m1b = hl ? g3b : g2b;
    u32x4 A0 = { hl ? e0a : m0a, hl ? e0b : m0b, hl ? m0a : e0a, hl ? m0b : e0b };
    u32x4 A1 = { hl ? e1a : m1a, hl ? e1b : m1b, hl ? m1a : e1a, hl ? m1b : e1b };
    bf16x8 pa0 = __builtin_bit_cast(bf16x8, A0);
    bf16x8 pa1 = __builtin_bit_cast(bf16x8, A1);
    acc0 = __builtin_amdgcn_mfma_f32_32x32x16_bf16(vf00, pa0, acc0, 0, 0, 0);
    acc0 = __builtin_amdgcn_mfma_f32_32x32x16_bf16(vf10, pa1, acc0, 0, 0, 0);
    acc1 = __builtin_amdgcn_mfma_f32_32x32x16_bf16(vf01, pa0, acc1, 0, 0, 0);
    acc1 = __builtin_amdgcn_mfma_f32_32x32x16_bf16(vf11, pa1, acc1, 0, 0, 0);
    kc0 = kn0; kc1 = kn1; kc2 = kn2; kc3 = kn3;   // rotate prefetched K in
  }
  // epilogue: merge lane-pair denominators, normalize, transpose via LDS, store
  l += __shfl_xor(l, 32);
  float inv = __builtin_amdgcn_rcpf(l);
  char* tbc = (char*)tp;
  #pragma unroll
  for (int r = 0; r < 16; ++r){
    int d0 = (r & 3) + 8*(r >> 2) + 4*hl;
    *(u16*)(tbc + lq*128 + ((2*d0)      ^ ((lq & 7) << 4))) = f2bf(acc0[r] * inv);
    *(u16*)(tbc + lq*128 + ((2*(d0+32)) ^ ((lq & 7) << 4))) = f2bf(acc1[r] * inv);
  }
  int qr2 = lane >> 1, chb = (lane & 1) * 4;
  u16* cp = ctx + (size_t)(b*SEQ + q0 + qr2)*D_MODEL + h*HEAD_DIM;
  #pragma unroll
  for (int i = 0; i < 4; ++i){
    int ch = chb + i;
    u16x8 vv = *(const u16x8*)(tbc + qr2*128 + 16*(ch ^ (qr2 & 7)));
    *(u16x8*)&cp[ch*8] = vv;
  }
}

extern "C" void kernel_launch(void* const* d_in, const int* in_sizes, int n_in,
                              void* d_out, int out_size, void* d_ws, size_t ws_size,
                              hipStream_t stream){
  const float* x  = (const float*)d_in[0];
  const int*  pos = (const int*)d_in[1];
  const float* Wq = (const float*)d_in[2];
  const float* Wk = (const float*)d_in[3];
  const float* Wv = (const float*)d_in[4];
  const float* Wo = (const float*)d_in[5];
  float* out = (float*)d_out;
  char* ws = (char*)d_ws;
  u16* xb   = (u16*)(ws);                    // 16 MB  x bf16 (reused as ctx later)
  u16* wt   = (u16*)(ws + 16777216);         // 8 MB   Wt q,k,v,o transposed bf16
  u16* qb   = (u16*)(ws + 25165824);         // 16 MB  q row-major (roped, scaled)
  u16* kbh  = (u16*)(ws + 41943040);         // 16 MB  k [b][h][s][64] (roped)
  u16* vt2  = (u16*)(ws + 58720256);         // 16 MB  v [b][h][s/16][d][16]
  float2* tab = (float2*)(ws + 75497472);    // 512 KB rope table
  u16* ctxb = xb;

  k_cvt_x<<<(MROWS*D_MODEL/4)/256, 256, 0, stream>>>(x, xb, MROWS*D_MODEL/4);
  k_transpose_w<<<dim3(32,32,4), dim3(32,8), 0, stream>>>(Wq, Wk, Wv, Wo, wt);
  k_rope_tab<<<(SEQ*32)/256, 256, 0, stream>>>(pos, tab);
  k_gemm2<0><<<dim3(64,24), 256, 0, stream>>>(xb, wt, tab, qb, kbh, vt2, nullptr);
  k_attn<<<dim3(4096), 64, 0, stream>>>(qb, kbh, vt2, ctxb);
  k_gemm2<1><<<dim3(64,8), 256, 0, stream>>>(ctxb, wt + 3145728, nullptr, nullptr, nullptr, nullptr, out);
}

// Round 6
// 184.089 us; speedup vs baseline: 3.2060x; 1.1420x over previous
//
#include <hip/hip_runtime.h>

typedef unsigned short u16;
typedef unsigned int   u32;
typedef __bf16  bf16x8 __attribute__((ext_vector_type(8)));
typedef float   f32x4  __attribute__((ext_vector_type(4)));
typedef float   f32x16 __attribute__((ext_vector_type(16)));
typedef u16     u16x4  __attribute__((ext_vector_type(4)));
typedef u16     u16x8  __attribute__((ext_vector_type(8)));
typedef u32     u32x4  __attribute__((ext_vector_type(4)));

#define D_MODEL 1024
#define N_HEADS 16
#define HEAD_DIM 64
#define BATCH 4
#define SEQ 2048
#define MROWS (BATCH*SEQ)

__device__ __forceinline__ u16 f2bf(float f){
  unsigned u = __builtin_bit_cast(unsigned, f);
  u += 0x7fffu + ((u >> 16) & 1u);
  return (u16)(u >> 16);
}
__device__ __forceinline__ float bf2f(u16 h){
  unsigned u = ((unsigned)h) << 16;
  return __builtin_bit_cast(float, u);
}
__device__ __forceinline__ u32 cvtpk(float a, float b){
  u32 r; asm("v_cvt_pk_bf16_f32 %0, %1, %2" : "=v"(r) : "v"(a), "v"(b)); return r;
}
__device__ __forceinline__ void gload_lds16(const u16* g, u16* l){
  __builtin_amdgcn_global_load_lds((const __attribute__((address_space(1))) void*)g,
                                   (__attribute__((address_space(3))) void*)l, 16, 0, 0);
}

// ---------- x fp32 -> bf16 ----------
__global__ void k_cvt_x(const float* __restrict__ x, u16* __restrict__ xb, int n4){
  int i = blockIdx.x * 256 + threadIdx.x;
  if (i >= n4) return;
  float4 v = reinterpret_cast<const float4*>(x)[i];
  u16x4 o;
  o.x = f2bf(v.x); o.y = f2bf(v.y); o.z = f2bf(v.z); o.w = f2bf(v.w);
  *reinterpret_cast<u16x4*>(xb + (size_t)i * 4) = o;
}

// ---------- W fp32 [k][n] -> bf16 Wt [n][k] ----------
__global__ void k_transpose_w(const float* __restrict__ Wq, const float* __restrict__ Wk,
                              const float* __restrict__ Wv, const float* __restrict__ Wo,
                              u16* __restrict__ wt){
  __shared__ float t[32][33];
  int z = blockIdx.z;
  const float* W = (z==0)?Wq:(z==1)?Wk:(z==2)?Wv:Wo;
  u16* O = wt + (size_t)z * (D_MODEL*(size_t)D_MODEL);
  int n0 = blockIdx.x*32, k0 = blockIdx.y*32;
  int tx = threadIdx.x, ty = threadIdx.y;
  #pragma unroll
  for (int i = ty; i < 32; i += 8) t[i][tx] = W[(size_t)(k0+i)*D_MODEL + n0 + tx];
  __syncthreads();
  #pragma unroll
  for (int i = ty; i < 32; i += 8) O[(size_t)(n0+i)*D_MODEL + k0 + tx] = f2bf(t[tx][i]);
}

// ---------- RoPE cos/sin table ----------
__global__ void k_rope_tab(const int* __restrict__ pos, float2* __restrict__ tab){
  int i = blockIdx.x * 256 + threadIdx.x;          // SEQ*32 threads
  int s = i >> 5, f = i & 31;
  float inv = exp2f(-(float)f * (13.287712379549449f / 32.0f)); // theta^(-f/32)
  float a = (float)pos[s] * inv;
  float sn, cs;
  sincosf(a, &sn, &cs);
  tab[i] = make_float2(cs, sn);
}

// ---------- 2-phase double-buffered GEMM, 128x128 tile, BK=32, 4 waves ----------
// MODE 0: fused QKV (RoPE fold, q/k/v routed outputs). MODE 1: f32 out (Wo).
template<int MODE>
__global__ __launch_bounds__(256, 4) void k_gemm2(const u16* __restrict__ A, const u16* __restrict__ Bt,
                                                  const float2* __restrict__ tab,
                                                  u16* __restrict__ qout, u16* __restrict__ kout,
                                                  u16* __restrict__ vout, float* __restrict__ fout){
  __shared__ u16 sA0[128*32], sA1[128*32], sB0[128*32], sB1[128*32];   // 32 KB dbuf
  const int K = 1024;
  int tid = threadIdx.x, lane = tid & 63, w = tid >> 6;
  int lr = lane & 15, lg = lane >> 4;
  int m0 = blockIdx.x * 128, n0 = blockIdx.y * 128;
  int wm = w >> 1, wn = w & 1;
  int srow = lane >> 2, scol = (lane & 3) * 8;
  const u16* ga = A  + (size_t)(m0 + w*16 + srow)*K + scol;   // + i*64*K + t*32
  const u16* gb = Bt + (size_t)(n0 + w*16 + srow)*K + scol;
  f32x4 acc[4][4] = {};

#define STAGE2(t, sa, sb) \
    gload_lds16(ga + (size_t)(t)*32,         sa + (w*16)*32); \
    gload_lds16(ga + (size_t)(t)*32 + 64*K,  sa + (64 + w*16)*32); \
    gload_lds16(gb + (size_t)(t)*32,         sb + (w*16)*32); \
    gload_lds16(gb + (size_t)(t)*32 + 64*K,  sb + (64 + w*16)*32);

#define COMP2(sa, sb) { \
    bf16x8 af[4], bv[4]; \
    _Pragma("unroll") \
    for (int mi = 0; mi < 4; mi++) \
      af[mi] = *(const bf16x8*)&sa[(wm*64 + mi*16 + lr)*32 + lg*8]; \
    _Pragma("unroll") \
    for (int ni = 0; ni < 4; ni++) \
      bv[ni] = *(const bf16x8*)&sb[(wn*64 + ni*16 + lr)*32 + lg*8]; \
    _Pragma("unroll") \
    for (int mi = 0; mi < 4; mi++){ \
      _Pragma("unroll") \
      for (int ni = 0; ni < 4; ni++) \
        acc[mi][ni] = __builtin_amdgcn_mfma_f32_16x16x32_bf16(af[mi], bv[ni], acc[mi][ni], 0, 0, 0); \
    } }

  STAGE2(0, sA0, sB0);
  __syncthreads();
  for (int t2 = 0; t2 < 16; ++t2){
    int t = t2 * 2;
    STAGE2(t+1, sA1, sB1);       // issue next-tile loads BEFORE computing current
    COMP2(sA0, sB0);
    __syncthreads();             // drains this wave's vmcnt; all stages landed
    if (t + 2 < 32){ STAGE2(t+2, sA0, sB0); }
    COMP2(sA1, sB1);
    __syncthreads();
  }
#undef STAGE2
#undef COMP2

  #pragma unroll
  for (int mi = 0; mi < 4; mi++){
    int row = m0 + wm*64 + mi*16 + lg*4;
    #pragma unroll
    for (int ni = 0; ni < 4; ni++){
      int col = n0 + wn*64 + ni*16 + lr;
      f32x4 vv = acc[mi][ni];
      if (MODE == 1){
        #pragma unroll
        for (int r = 0; r < 4; r++)
          fout[(size_t)(row + r)*1024 + col] = vv[r];
      } else {
        int cm = col & 1023;
        int hh = cm >> 6, d = cm & 63;
        const int which = n0 >> 10;             // 0=q 1=k 2=v
        #pragma unroll
        for (int r = 0; r < 4; r++){
          int rr = row + r;
          int bb = rr >> 11, s = rr & (SEQ-1);
          float val = vv[r];
          if (which < 2){
            float partner = __shfl_xor(val, 1);
            float2 cs = tab[s*32 + (d >> 1)];
            float o = (d & 1) ? (partner*cs.y + val*cs.x) : (val*cs.x - partner*cs.y);
            if (which == 0){
              o *= 0.18033688011112042f;        // 0.125 * log2(e)
              qout[(size_t)rr*1024 + cm] = f2bf(o);
            } else {
              kout[(((size_t)(bb*N_HEADS + hh))*SEQ + s)*64 + d] = f2bf(o);
            }
          } else {
            vout[(((size_t)(bb*N_HEADS + hh))*(SEQ/16) + (s >> 4))*1024 + d*16 + (s & 15)] = f2bf(val);
          }
        }
      }
    }
  }
}

// ---------- causal flash attention: 4-wave blocks, K/V shared via LDS dbuf ----------
// grid 1024 x 256 thr. Block B: bh = B&63 (XCD = bh&7 preserved), g = 15-(B>>6)
// (longest blocks first). Wave w handles q-tile qi = 4g+w (32 rows).
// Per j-tile (32 keys): K 4KB (XOR-swizzled via pre-swizzled global src) + V 4KB
// staged cooperatively, double-buffered; stage(j+1) issued before compute(j).
__global__ __launch_bounds__(256, 3) void k_attn(const u16* __restrict__ q, const u16* __restrict__ k2,
                                                 const u16* __restrict__ v2, u16* __restrict__ ctx){
  __shared__ u16 kv[2][4096];                 // per buf: K 4KB | V 4KB
  const int lane = threadIdx.x & 63, w = threadIdx.x >> 6;
  const int lq = lane & 31, hl = lane >> 5;
  const int B = blockIdx.x;
  const int bh = B & 63, g = 15 - (B >> 6);
  const int b = bh >> 4, h = bh & 15;
  const int qi = 4*g + w;
  const int q0 = qi * 32;
  const int qmax0 = (4*g + 3) * 32;           // block-uniform loop bound
  const u16* kglob = k2 + (size_t)bh*SEQ*64;
  const u16* vglob = v2 + (size_t)bh*(SEQ/16)*1024;

  const u16* qr_ = q + (size_t)(b*SEQ + q0 + lq)*D_MODEL + h*HEAD_DIM + hl*8;
  bf16x8 qf0 = *(const bf16x8*)&qr_[0];
  bf16x8 qf1 = *(const bf16x8*)&qr_[16];
  bf16x8 qf2 = *(const bf16x8*)&qr_[32];
  bf16x8 qf3 = *(const bf16x8*)&qr_[48];
  f32x16 acc0 = {}, acc1 = {};
  float m = -3.0e38f, l = 0.f;

  // stage lambda: K rows jt..jt+31 swizzled (LDS[row][c] = K[row][c ^ (row&7)]), V linear
  auto STAGE = [&](int bf, int jt){
    const u16* ks = kglob + (size_t)(jt + (w<<3) + (lane>>3))*64 + (((lane&7)^(lane>>3))<<3);
    gload_lds16(ks, &kv[bf][w<<9]);
    const u16* vs = vglob + ((size_t)(jt>>4)<<10) + (w<<9) + (lane<<3);
    gload_lds16(vs, &kv[bf][2048 + (w<<9)]);
  };

  STAGE(0, 0);
  __syncthreads();                            // barrier drains vmcnt: buf0 ready
  int p = 0;
  for (int j0 = 0; j0 <= qmax0; j0 += 32){
    if (j0 + 32 <= qmax0) STAGE(p^1, j0 + 32);
    if (j0 <= q0){
      const char* kb = (const char*)&kv[p][0];
      bf16x8 kf0 = *(const bf16x8*)(kb + lq*128 + (((0+hl) ^ (lq&7))<<4));
      bf16x8 kf1 = *(const bf16x8*)(kb + lq*128 + (((2+hl) ^ (lq&7))<<4));
      bf16x8 kf2 = *(const bf16x8*)(kb + lq*128 + (((4+hl) ^ (lq&7))<<4));
      bf16x8 kf3 = *(const bf16x8*)(kb + lq*128 + (((6+hl) ^ (lq&7))<<4));
      const char* vb = kb + 4096;
      bf16x8 vf00 = *(const bf16x8*)(vb + lq*32 + hl*16);
      bf16x8 vf01 = *(const bf16x8*)(vb + lq*32 + hl*16 + 1024);
      bf16x8 vf10 = *(const bf16x8*)(vb + lq*32 + hl*16 + 2048);
      bf16x8 vf11 = *(const bf16x8*)(vb + lq*32 + hl*16 + 3072);

      f32x16 S = {};
      S = __builtin_amdgcn_mfma_f32_32x32x16_bf16(kf0, qf0, S, 0, 0, 0);
      S = __builtin_amdgcn_mfma_f32_32x32x16_bf16(kf1, qf1, S, 0, 0, 0);
      S = __builtin_amdgcn_mfma_f32_32x32x16_bf16(kf2, qf2, S, 0, 0, 0);
      S = __builtin_amdgcn_mfma_f32_32x32x16_bf16(kf3, qf3, S, 0, 0, 0);

      if (j0 == q0){                          // diagonal tile: mask k > q
        #pragma unroll
        for (int r = 0; r < 16; ++r){
          int kk = (r & 3) + 8*(r >> 2) + 4*hl;
          if (kk > lq) S[r] = -3.0e38f;
        }
      }
      float a0 = fmaxf(fmaxf(S[0],S[1]),  fmaxf(S[2],S[3]));
      float a1 = fmaxf(fmaxf(S[4],S[5]),  fmaxf(S[6],S[7]));
      float a2 = fmaxf(fmaxf(S[8],S[9]),  fmaxf(S[10],S[11]));
      float a3 = fmaxf(fmaxf(S[12],S[13]),fmaxf(S[14],S[15]));
      float pm = fmaxf(fmaxf(a0,a1), fmaxf(a2,a3));
      pm = fmaxf(pm, __shfl_xor(pm, 32));
      if (__any(pm > m + 8.f)){               // defer-max (T13)
        float mn = fmaxf(m, pm);
        float cr = __builtin_amdgcn_exp2f(m - mn);
        l *= cr;
        #pragma unroll
        for (int r = 0; r < 16; ++r){ acc0[r] *= cr; acc1[r] *= cr; }
        m = mn;
      }
      #pragma unroll
      for (int r = 0; r < 16; ++r) S[r] = __builtin_amdgcn_exp2f(S[r] - m);   // P in place
      float s0_ = (S[0]+S[1]) + (S[2]+S[3]);
      float s1_ = (S[4]+S[5]) + (S[6]+S[7]);
      float s2_ = (S[8]+S[9]) + (S[10]+S[11]);
      float s3_ = (S[12]+S[13]) + (S[14]+S[15]);
      l += (s0_+s1_) + (s2_+s3_);             // per-lane partial (merged in epilogue)
      // pack P -> bf16 pairs (cvt_pk); exchange with lane^32 to build A-fragments
      u32 g0a = cvtpk(S[0], S[1]),  g0b = cvtpk(S[2], S[3]);
      u32 g1a = cvtpk(S[4], S[5]),  g1b = cvtpk(S[6], S[7]);
      u32 g2a = cvtpk(S[8], S[9]),  g2b = cvtpk(S[10],S[11]);
      u32 g3a = cvtpk(S[12],S[13]), g3b = cvtpk(S[14],S[15]);
      u32 s0a = hl ? g0a : g1a, s0b = hl ? g0b : g1b;
      u32 e0a = (u32)__shfl_xor((int)s0a, 32), e0b = (u32)__shfl_xor((int)s0b, 32);
      u32 m0a = hl ? g1a : g0a, m0b = hl ? g1b : g0b;
      u32 s1a = hl ? g2a : g3a, s1b = hl ? g2b : g3b;
      u32 e1a = (u32)__shfl_xor((int)s1a, 32), e1b = (u32)__shfl_xor((int)s1b, 32);
      u32 m1a = hl ? g3a : g2a, m1b = hl ? g3b : g2b;
      u32x4 A0 = { hl ? e0a : m0a, hl ? e0b : m0b, hl ? m0a : e0a, hl ? m0b : e0b };
      u32x4 A1 = { hl ? e1a : m1a, hl ? e1b : m1b, hl ? m1a : e1a, hl ? m1b : e1b };
      bf16x8 pa0 = __builtin_bit_cast(bf16x8, A0);
      bf16x8 pa1 = __builtin_bit_cast(bf16x8, A1);
      acc0 = __builtin_amdgcn_mfma_f32_32x32x16_bf16(vf00, pa0, acc0, 0, 0, 0);
      acc0 = __builtin_amdgcn_mfma_f32_32x32x16_bf16(vf10, pa1, acc0, 0, 0, 0);
      acc1 = __builtin_amdgcn_mfma_f32_32x32x16_bf16(vf01, pa0, acc1, 0, 0, 0);
      acc1 = __builtin_amdgcn_mfma_f32_32x32x16_bf16(vf11, pa1, acc1, 0, 0, 0);
    }
    __syncthreads();                          // drains vmcnt (stages landed) + frees buf[p]
    p ^= 1;
  }
  // epilogue: merge lane-pair denominators, normalize, transpose via LDS, store
  // (all waves exit loop together; kv reused as per-wave 4KB transpose buffers)
  l += __shfl_xor(l, 32);
  float inv = __builtin_amdgcn_rcpf(l);
  char* tbc = (char*)kv + w*4096;
  #pragma unroll
  for (int r = 0; r < 16; ++r){
    int d0 = (r & 3) + 8*(r >> 2) + 4*hl;
    *(u16*)(tbc + lq*128 + ((2*d0)      ^ ((lq & 7) << 4))) = f2bf(acc0[r] * inv);
    *(u16*)(tbc + lq*128 + ((2*(d0+32)) ^ ((lq & 7) << 4))) = f2bf(acc1[r] * inv);
  }
  int qr2 = lane >> 1, chb = (lane & 1) * 4;
  u16* cp = ctx + (size_t)(b*SEQ + q0 + qr2)*D_MODEL + h*HEAD_DIM;
  #pragma unroll
  for (int i = 0; i < 4; ++i){
    int ch = chb + i;
    u16x8 vv = *(const u16x8*)(tbc + qr2*128 + 16*(ch ^ (qr2 & 7)));
    *(u16x8*)&cp[ch*8] = vv;
  }
}

extern "C" void kernel_launch(void* const* d_in, const int* in_sizes, int n_in,
                              void* d_out, int out_size, void* d_ws, size_t ws_size,
                              hipStream_t stream){
  const float* x  = (const float*)d_in[0];
  const int*  pos = (const int*)d_in[1];
  const float* Wq = (const float*)d_in[2];
  const float* Wk = (const float*)d_in[3];
  const float* Wv = (const float*)d_in[4];
  const float* Wo = (const float*)d_in[5];
  float* out = (float*)d_out;
  char* ws = (char*)d_ws;
  u16* xb   = (u16*)(ws);                    // 16 MB  x bf16 (reused as ctx later)
  u16* wt   = (u16*)(ws + 16777216);         // 8 MB   Wt q,k,v,o transposed bf16
  u16* qb   = (u16*)(ws + 25165824);         // 16 MB  q row-major (roped, scaled)
  u16* kbh  = (u16*)(ws + 41943040);         // 16 MB  k [b][h][s][64] (roped)
  u16* vt2  = (u16*)(ws + 58720256);         // 16 MB  v [b][h][s/16][d][16]
  float2* tab = (float2*)(ws + 75497472);    // 512 KB rope table
  u16* ctxb = xb;

  k_cvt_x<<<(MROWS*D_MODEL/4)/256, 256, 0, stream>>>(x, xb, MROWS*D_MODEL/4);
  k_transpose_w<<<dim3(32,32,4), dim3(32,8), 0, stream>>>(Wq, Wk, Wv, Wo, wt);
  k_rope_tab<<<(SEQ*32)/256, 256, 0, stream>>>(pos, tab);
  k_gemm2<0><<<dim3(64,24), 256, 0, stream>>>(xb, wt, tab, qb, kbh, vt2, nullptr);
  k_attn<<<dim3(1024), 256, 0, stream>>>(qb, kbh, vt2, ctxb);
  k_gemm2<1><<<dim3(64,8), 256, 0, stream>>>(ctxb, wt + 3145728, nullptr, nullptr, nullptr, nullptr, out);
}